// Round 7
// baseline (493.593 us; speedup 1.0000x reference)
//
#include <hip/hip_runtime.h>
#include <cstddef>
#include <cstdint>

constexpr int Bn = 8;
constexpr int Ln = 2048;
constexpr int Dn = 1024;
constexpr float MASKED_VAL = -2147483648.0f;  // -2^31

typedef unsigned short u16;
typedef unsigned int   u32;
typedef __attribute__((ext_vector_type(8))) __bf16 bf16x8;
typedef __attribute__((ext_vector_type(4))) float  f32x4;

__device__ __forceinline__ u16 f2bf(float x) {
    u32 u = __float_as_uint(x);
    u += 0x7FFFu + ((u >> 16) & 1u);
    return (u16)(u >> 16);
}
__device__ __forceinline__ float bf2f(u16 h) {
    return __uint_as_float(((u32)h) << 16);
}
__device__ __forceinline__ u32 pack2(float a, float b) {
    return (u32)f2bf(a) | ((u32)f2bf(b) << 16);
}
__device__ __forceinline__ int rup(int x, int m) { return (x + m - 1) & ~(m - 1); }

__device__ __forceinline__ void gload16(const void* g, void* l) {
    typedef const __attribute__((address_space(1))) unsigned int* gp_t;
    typedef __attribute__((address_space(3))) unsigned int* lp_t;
    __builtin_amdgcn_global_load_lds((gp_t)g, (lp_t)l, 16, 0, 0);
}

#define MFMA16(a, b, c) __builtin_amdgcn_mfma_f32_16x16x32_bf16((a), (b), (c), 0, 0, 0)

// ---------------------------------------------------------------------------
// prep: per batch, compact index lists for k_mask (kidx + inverse kpos) and
// q_mask (qidx), plus counts. Pads kidx with last valid index, qidx with 0.
// ---------------------------------------------------------------------------
__global__ __launch_bounds__(256) void prep_kernel(
    const int* __restrict__ k_mask, const int* __restrict__ q_mask,
    int* __restrict__ kidx, int* __restrict__ kpos,
    int* __restrict__ qidx, int* __restrict__ cnts)
{
    __shared__ int sc[256];
    __shared__ int lastv;
    const int b = blockIdx.x, t = threadIdx.x;
    for (int pass = 0; pass < 2; ++pass) {
        const int* msk = (pass ? q_mask : k_mask) + b * Ln;
        int* idx = (pass ? qidx : kidx) + b * Ln;
        int f[8], s = 0;
        #pragma unroll
        for (int j = 0; j < 8; ++j) { f[j] = (msk[t * 8 + j] != 0) ? 1 : 0; s += f[j]; }
        sc[t] = s;
        __syncthreads();
        #pragma unroll
        for (int o = 1; o < 256; o <<= 1) {
            int v = (t >= o) ? sc[t - o] : 0;
            __syncthreads();
            sc[t] += v;
            __syncthreads();
        }
        int incl = sc[t];
        int total = sc[255];
        int p = incl - s;
        #pragma unroll
        for (int j = 0; j < 8; ++j) {
            if (pass == 0) kpos[b * Ln + t * 8 + j] = f[j] ? p : 0;
            if (f[j]) { idx[p] = t * 8 + j; ++p; }
        }
        __syncthreads();
        if (t == 0) {
            cnts[b * 2 + pass] = total;
            lastv = (total > 0) ? idx[total - 1] : 0;
        }
        __syncthreads();
        int padv = (pass == 0) ? lastv : 0;
        for (int e2 = total + t; e2 < Ln; e2 += 256) idx[e2] = padv;
        __syncthreads();
    }
}

// ---------------------------------------------------------------------------
// convert3: fp32 -> bf16 for three equally-sized arrays in one launch.
// ---------------------------------------------------------------------------
__global__ __launch_bounds__(256) void convert3_kernel(
    const float* __restrict__ s0, const float* __restrict__ s1, const float* __restrict__ s2,
    u16* __restrict__ d0, u16* __restrict__ d1, u16* __restrict__ d2, int blocksPer)
{
    int id = blockIdx.x;
    int which = id / blocksPer;
    int off = id - which * blocksPer;
    const float* src = (which == 0) ? s0 : (which == 1) ? s1 : s2;
    u16* dst = (which == 0) ? d0 : (which == 1) ? d1 : d2;
    int i = (off * 256 + threadIdx.x) * 8;
    float f[8];
    *(float4*)&f[0] = *(const float4*)(src + i);
    *(float4*)&f[4] = *(const float4*)(src + i + 4);
    u32 H[4];
    #pragma unroll
    for (int j = 0; j < 4; ++j) H[j] = pack2(f[2*j], f[2*j+1]);
    *(uint4*)(dst + i) = make_uint4(H[0], H[1], H[2], H[3]);
}

__global__ __launch_bounds__(256) void convert_single_kernel(
    const float* __restrict__ src, u16* __restrict__ dh, int n)
{
    int i = (blockIdx.x * 256 + threadIdx.x) * 8;
    if (i >= n) return;
    float f[8];
    *(float4*)&f[0] = *(const float4*)(src + i);
    *(float4*)&f[4] = *(const float4*)(src + i + 4);
    u32 H[4];
    #pragma unroll
    for (int j = 0; j < 4; ++j) H[j] = pack2(f[2*j], f[2*j+1]);
    *(uint4*)(dh + i) = make_uint4(H[0], H[1], H[2], H[3]);
}

// ---------------------------------------------------------------------------
// wtrans: W (fp32 [e][d]) -> Wt (bf16 [d][e]) for Wq and Wk (z selects).
// ---------------------------------------------------------------------------
__global__ __launch_bounds__(256) void wtrans_kernel(
    const float* __restrict__ Wq, const float* __restrict__ Wk,
    u16* __restrict__ Wqt, u16* __restrict__ Wkt)
{
    __shared__ float tile[64][68];
    const float* src = blockIdx.z ? Wk : Wq;
    u16* dst = blockIdx.z ? Wkt : Wqt;
    const int e0 = blockIdx.y * 64, d0 = blockIdx.x * 64;
    const int t = threadIdx.x;
    const int r = t >> 2, cq = (t & 3) * 16;
    const float* s = src + (size_t)(e0 + r) * Dn + d0 + cq;
    #pragma unroll
    for (int i = 0; i < 4; ++i)
        *(float4*)&tile[r][cq + i * 4] = *(const float4*)(s + i * 4);
    __syncthreads();
    u32 o[8];
    #pragma unroll
    for (int i = 0; i < 8; ++i)
        o[i] = pack2(tile[cq + 2 * i][r], tile[cq + 2 * i + 1][r]);
    u16* d = dst + (size_t)(d0 + r) * Dn + e0 + cq;
    *(uint4*)(d)     = make_uint4(o[0], o[1], o[2], o[3]);
    *(uint4*)(d + 8) = make_uint4(o[4], o[5], o[6], o[7]);
}

// ---------------------------------------------------------------------------
// ck: cbuf[0] = bq . bk
// ---------------------------------------------------------------------------
__global__ __launch_bounds__(64) void ck_kernel(
    const float* __restrict__ bq, const float* __restrict__ bk, float* __restrict__ cbuf)
{
    int l = threadIdx.x;
    float s = 0.f;
    #pragma unroll
    for (int i = 0; i < 16; ++i) s += bq[l + 64 * i] * bk[l + 64 * i];
    #pragma unroll
    for (int o = 32; o; o >>= 1) s += __shfl_xor(s, o, 64);
    if (l == 0) cbuf[0] = s;
}

// ---------------------------------------------------------------------------
// wvec: w1[d] = Wqt[d,:].bk ; w2[d] = Wkt[d,:].bq   (one wave per d)
// ---------------------------------------------------------------------------
__global__ __launch_bounds__(256) void wvec_kernel(
    const u16* __restrict__ Wqt, const u16* __restrict__ Wkt,
    const float* __restrict__ bk, const float* __restrict__ bq,
    float* __restrict__ w1, float* __restrict__ w2)
{
    const int y = blockIdx.y;
    const u16* src = y ? Wkt : Wqt;
    const float* vec = y ? bq : bk;
    float* out = y ? w2 : w1;
    const int d = blockIdx.x * 4 + (threadIdx.x >> 6);
    const int l = threadIdx.x & 63;
    float s = 0.f;
    #pragma unroll
    for (int i = 0; i < 16; ++i) {
        int e = l + 64 * i;
        s += bf2f(src[(size_t)d * Dn + e]) * vec[e];
    }
    #pragma unroll
    for (int o = 32; o; o >>= 1) s += __shfl_xor(s, o, 64);
    if (l == 0) out[d] = s;
}

// ---------------------------------------------------------------------------
// rowdot: u[row] = Xq[row,:].w1 + c ; v[row] = Xk[row,:].w2  (one wave/row)
// ---------------------------------------------------------------------------
__global__ __launch_bounds__(256) void rowdot_kernel(
    const u16* __restrict__ Xq, const u16* __restrict__ Xk,
    const float* __restrict__ w1, const float* __restrict__ w2,
    const float* __restrict__ cbuf, float* __restrict__ u, float* __restrict__ v)
{
    const int y = blockIdx.y;
    const u16* x = y ? Xk : Xq;
    const float* w = y ? w2 : w1;
    float* out = y ? v : u;
    const int row = blockIdx.x * 4 + (threadIdx.x >> 6);
    const int l = threadIdx.x & 63;
    float s = 0.f;
    #pragma unroll
    for (int h = 0; h < 2; ++h) {
        const u16* xp = x + (size_t)row * Dn + h * 512 + l * 8;
        const float* wp = w + h * 512 + l * 8;
        uint4 xv = *(const uint4*)xp;
        float4 wa = *(const float4*)(wp);
        float4 wb = *(const float4*)(wp + 4);
        const u16* xs = (const u16*)&xv;
        s += bf2f(xs[0]) * wa.x + bf2f(xs[1]) * wa.y + bf2f(xs[2]) * wa.z + bf2f(xs[3]) * wa.w
           + bf2f(xs[4]) * wb.x + bf2f(xs[5]) * wb.y + bf2f(xs[6]) * wb.z + bf2f(xs[7]) * wb.w;
    }
    #pragma unroll
    for (int o = 32; o; o >>= 1) s += __shfl_xor(s, o, 64);
    if (l == 0) out[row] = s + (y ? 0.0f : cbuf[0]);
}

// ---------------------------------------------------------------------------
// vcg: vc[b,j] = v[b, kidx[b,j]]
// ---------------------------------------------------------------------------
__global__ __launch_bounds__(256) void vcg_kernel(
    const float* __restrict__ v, const int* __restrict__ kidx, float* __restrict__ vc)
{
    const int b = blockIdx.x;
    for (int j = threadIdx.x; j < Ln; j += 256)
        vc[b * Ln + j] = v[b * Ln + kidx[b * Ln + j]];
}

// ---------------------------------------------------------------------------
// zeroa: zero a-rows where q_mask==0 (pvc writes all other rows fully).
// ---------------------------------------------------------------------------
__global__ __launch_bounds__(256) void zeroa_kernel(
    float4* __restrict__ out_a, const int* __restrict__ q_mask)
{
    const int row = blockIdx.x;
    if (q_mask[row]) return;
    out_a[(size_t)row * 256 + threadIdx.x] = make_float4(0.f, 0.f, 0.f, 0.f);
}

// ---------------------------------------------------------------------------
// mgemm: Mt[d'][d] = sum_e Wkt[d',e] * Wqt[d,e]   (1024x1024x1024, bf16 out)
// ---------------------------------------------------------------------------
__global__ __launch_bounds__(256) void mgemm_kernel(
    const u16* __restrict__ Wkt, const u16* __restrict__ Wqt, u16* __restrict__ Mt)
{
    __shared__ __align__(16) unsigned char As[128 * 128];
    __shared__ __align__(16) unsigned char Bs[128 * 128];

    const int m0 = blockIdx.y * 128, n0 = blockIdx.x * 128;
    const int tid = threadIdx.x, lane = tid & 63, wid = tid >> 6;
    const int wm = (wid >> 1) * 64, wn = (wid & 1) * 64;

    const u16* gA[4]; const u16* gB[4]; int ldsOff[4];
    #pragma unroll
    for (int q = 0; q < 4; ++q) {
        int c = wid * 4 + q;
        int row = c * 8 + (lane >> 3);
        int sig = (lane & 7) ^ (row & 7);
        gA[q] = Wkt + (size_t)(m0 + row) * Dn + sig * 8;
        gB[q] = Wqt + (size_t)(n0 + row) * Dn + sig * 8;
        ldsOff[q] = c * 1024;
    }

    f32x4 acc[4][4];
    const f32x4 z4 = {0.f, 0.f, 0.f, 0.f};
    #pragma unroll
    for (int i = 0; i < 4; ++i)
        #pragma unroll
        for (int j = 0; j < 4; ++j) acc[i][j] = z4;

    for (int k0 = 0; k0 < Dn; k0 += 64) {
        #pragma unroll
        for (int q = 0; q < 4; ++q) {
            gload16(gA[q], As + ldsOff[q]);
            gload16(gB[q], Bs + ldsOff[q]);
            gA[q] += 64; gB[q] += 64;
        }
        __syncthreads();

        const int sh = lane >> 4;
        #pragma unroll
        for (int s = 0; s < 2; ++s) {
            bf16x8 af[4], bf[4];
            #pragma unroll
            for (int i = 0; i < 4; ++i) {
                int row = wm + i * 16 + (lane & 15);
                af[i] = *(const bf16x8*)(As + row * 128 + (((s * 4 + sh) ^ (row & 7)) << 4));
            }
            #pragma unroll
            for (int j = 0; j < 4; ++j) {
                int row = wn + j * 16 + (lane & 15);
                bf[j] = *(const bf16x8*)(Bs + row * 128 + (((s * 4 + sh) ^ (row & 7)) << 4));
            }
            #pragma unroll
            for (int i = 0; i < 4; ++i)
                #pragma unroll
                for (int j = 0; j < 4; ++j)
                    acc[i][j] = MFMA16(af[i], bf[j], acc[i][j]);
        }
        __syncthreads();
    }

    #pragma unroll
    for (int i = 0; i < 4; ++i) {
        #pragma unroll
        for (int r = 0; r < 4; ++r) {
            int m = m0 + wm + i * 16 + (lane >> 4) * 4 + r;
            u16* oh = Mt + (size_t)m * Dn + n0 + wn;
            #pragma unroll
            for (int j = 0; j < 4; ++j)
                oh[j * 16 + (lane & 15)] = f2bf(acc[i][j][r]);
        }
    }
}

// ---------------------------------------------------------------------------
// proj2: z=0: Tb = Xq @ Mt^T (no bias) ; z=1: Vh = Vbf @ Wvb^T + bv.
// R5 grid mapping (round-robin XCD) -- swizzle hurt this kernel (R6).
// ---------------------------------------------------------------------------
__global__ __launch_bounds__(256) void proj2_kernel(
    const u16* __restrict__ Xq, const u16* __restrict__ Vbf,
    const u16* __restrict__ Mt, const u16* __restrict__ Wvb,
    const float* __restrict__ bv, u16* __restrict__ Tb, u16* __restrict__ Vh)
{
    __shared__ __align__(16) unsigned char As[128 * 128];
    __shared__ __align__(16) unsigned char Bs[128 * 128];

    const int z = blockIdx.z;
    const u16* X = z ? Vbf : Xq;
    const u16* W = z ? Wvb : Mt;
    const float* bias = z ? bv : nullptr;
    u16* C = z ? Vh : Tb;

    const int m0 = blockIdx.y * 128, n0 = blockIdx.x * 128;
    const int tid = threadIdx.x, lane = tid & 63, wid = tid >> 6;
    const int wm = (wid >> 1) * 64, wn = (wid & 1) * 64;

    const u16* gA[4]; const u16* gB[4]; int ldsOff[4];
    #pragma unroll
    for (int q = 0; q < 4; ++q) {
        int c = wid * 4 + q;
        int row = c * 8 + (lane >> 3);
        int sig = (lane & 7) ^ (row & 7);
        gA[q] = X + (size_t)(m0 + row) * Dn + sig * 8;
        gB[q] = W + (size_t)(n0 + row) * Dn + sig * 8;
        ldsOff[q] = c * 1024;
    }

    f32x4 acc[4][4];
    const f32x4 z4 = {0.f, 0.f, 0.f, 0.f};
    #pragma unroll
    for (int i = 0; i < 4; ++i)
        #pragma unroll
        for (int j = 0; j < 4; ++j) acc[i][j] = z4;

    for (int k0 = 0; k0 < Dn; k0 += 64) {
        #pragma unroll
        for (int q = 0; q < 4; ++q) {
            gload16(gA[q], As + ldsOff[q]);
            gload16(gB[q], Bs + ldsOff[q]);
            gA[q] += 64; gB[q] += 64;
        }
        __syncthreads();

        const int sh = lane >> 4;
        #pragma unroll
        for (int s = 0; s < 2; ++s) {
            bf16x8 af[4], bf[4];
            #pragma unroll
            for (int i = 0; i < 4; ++i) {
                int row = wm + i * 16 + (lane & 15);
                af[i] = *(const bf16x8*)(As + row * 128 + (((s * 4 + sh) ^ (row & 7)) << 4));
            }
            #pragma unroll
            for (int j = 0; j < 4; ++j) {
                int row = wn + j * 16 + (lane & 15);
                bf[j] = *(const bf16x8*)(Bs + row * 128 + (((s * 4 + sh) ^ (row & 7)) << 4));
            }
            #pragma unroll
            for (int i = 0; i < 4; ++i)
                #pragma unroll
                for (int j = 0; j < 4; ++j)
                    acc[i][j] = MFMA16(af[i], bf[j], acc[i][j]);
        }
        __syncthreads();
    }

    float bv4[4];
    #pragma unroll
    for (int j = 0; j < 4; ++j)
        bv4[j] = bias ? bias[n0 + wn + j * 16 + (lane & 15)] : 0.0f;
    #pragma unroll
    for (int i = 0; i < 4; ++i) {
        #pragma unroll
        for (int r = 0; r < 4; ++r) {
            int m = m0 + wm + i * 16 + (lane >> 4) * 4 + r;
            u16* oh = C + (size_t)m * Dn + n0 + wn;
            #pragma unroll
            for (int j = 0; j < 4; ++j)
                oh[j * 16 + (lane & 15)] = f2bf(acc[i][j][r] + bv4[j]);
        }
    }
}

// ---------------------------------------------------------------------------
// vtransc: Vtc[b][d][j] = Vh[b][kidx[b][j]][d]  (k-compacted transpose)
// ---------------------------------------------------------------------------
__global__ __launch_bounds__(256) void vtransc_kernel(
    const u16* __restrict__ Vh, const int* __restrict__ kidx,
    const int* __restrict__ cnts, u16* __restrict__ Vtc)
{
    __shared__ u16 tile[64][72];
    const int b = blockIdx.z;
    const int l0 = blockIdx.y * 64, d0 = blockIdx.x * 64;
    if (l0 >= rup(cnts[b * 2], 64)) return;
    const int t = threadIdx.x;
    const int r = t >> 2, cq = (t & 3) * 16;

    const int srcrow = kidx[b * Ln + l0 + r];
    const u16* src = Vh + (size_t)(b * Ln + srcrow) * Dn + d0 + cq;
    *(uint4*)&tile[r][cq]     = *(const uint4*)(src);
    *(uint4*)&tile[r][cq + 8] = *(const uint4*)(src + 8);
    __syncthreads();

    u16 tmp[16];
    #pragma unroll
    for (int i = 0; i < 16; ++i) tmp[i] = tile[cq + i][r];
    u16* dst = Vtc + (size_t)b * Dn * Ln + (size_t)(d0 + r) * Ln + l0 + cq;
    *(uint4*)(dst)     = *(uint4*)&tmp[0];
    *(uint4*)(dst + 8) = *(uint4*)&tmp[8];
}

// ---------------------------------------------------------------------------
// scorec: e'[b,q,j] = Tb[b,q,:] . Xk[b,kidx[j],:] + u[b,q] + vc[b,j]
// for compacted j < kc; pad cols get MASKED. XCD-chunked 1D grid (2048).
// ---------------------------------------------------------------------------
__global__ __launch_bounds__(256) void scorec_kernel(
    const u16* __restrict__ Tb, const u16* __restrict__ Xk,
    const int* __restrict__ kidx, const int* __restrict__ cnts,
    const float* __restrict__ u, const float* __restrict__ vc,
    float* __restrict__ out_e)
{
    __shared__ __align__(16) unsigned char As[128 * 128];
    __shared__ __align__(16) unsigned char Bs[128 * 128];

    // swizzle: nwg = 2048 = 8 * 256
    const int d = blockIdx.x;
    const int f = (d & 7) * 256 + (d >> 3);
    const int b = f >> 8;
    const int rem = f & 255;
    const int m0 = (rem >> 4) * 128;  // 16 q-tiles
    const int n0 = (rem & 15) * 128;  // 16 k-tiles

    const int kc_b = cnts[b * 2];
    if (n0 >= kc_b) return;
    const int tid = threadIdx.x, lane = tid & 63, wid = tid >> 6;
    const int wm = (wid >> 1) * 64, wn = (wid & 1) * 64;

    const size_t boff = (size_t)b * Ln * Dn;
    const u16* Tb_b = Tb + boff;
    const u16* Xk_b = Xk + boff;
    const int* kidx_b = kidx + b * Ln;

    const u16* gA[4]; const u16* gB[4]; int ldsOff[4];
    #pragma unroll
    for (int q = 0; q < 4; ++q) {
        int c = wid * 4 + q;
        int row = c * 8 + (lane >> 3);
        int sig = (lane & 7) ^ (row & 7);
        int grow = kidx_b[n0 + row];
        gA[q] = Tb_b + (size_t)(m0 + row) * Dn + sig * 8;
        gB[q] = Xk_b + (size_t)grow * Dn + sig * 8;
        ldsOff[q] = c * 1024;
    }

    f32x4 acc[4][4];
    const f32x4 z4 = {0.f, 0.f, 0.f, 0.f};
    #pragma unroll
    for (int i = 0; i < 4; ++i)
        #pragma unroll
        for (int j = 0; j < 4; ++j) acc[i][j] = z4;

    for (int k0 = 0; k0 < Dn; k0 += 64) {
        #pragma unroll
        for (int q = 0; q < 4; ++q) {
            gload16(gA[q], As + ldsOff[q]);
            gload16(gB[q], Bs + ldsOff[q]);
            gA[q] += 64; gB[q] += 64;
        }
        __syncthreads();

        const int sh = lane >> 4;
        #pragma unroll
        for (int s = 0; s < 2; ++s) {
            bf16x8 af[4], bf[4];
            #pragma unroll
            for (int i = 0; i < 4; ++i) {
                int row = wm + i * 16 + (lane & 15);
                af[i] = *(const bf16x8*)(As + row * 128 + (((s * 4 + sh) ^ (row & 7)) << 4));
            }
            #pragma unroll
            for (int j = 0; j < 4; ++j) {
                int row = wn + j * 16 + (lane & 15);
                bf[j] = *(const bf16x8*)(Bs + row * 128 + (((s * 4 + sh) ^ (row & 7)) << 4));
            }
            #pragma unroll
            for (int i = 0; i < 4; ++i)
                #pragma unroll
                for (int j = 0; j < 4; ++j)
                    acc[i][j] = MFMA16(af[i], bf[j], acc[i][j]);
        }
        __syncthreads();
    }

    float vcl[4];
    #pragma unroll
    for (int j = 0; j < 4; ++j) vcl[j] = vc[b * Ln + n0 + wn + j * 16 + (lane & 15)];
    #pragma unroll
    for (int i = 0; i < 4; ++i) {
        #pragma unroll
        for (int r = 0; r < 4; ++r) {
            int m = m0 + wm + i * 16 + (lane >> 4) * 4 + r;
            float um = u[b * Ln + m];
            float* orow = out_e + ((size_t)(b * Ln + m)) * Ln + n0 + wn;
            #pragma unroll
            for (int j = 0; j < 4; ++j) {
                int jj = n0 + wn + j * 16 + (lane & 15);
                orow[j * 16 + (lane & 15)] = (jj < kc_b) ? (acc[i][j][r] + um + vcl[j]) : MASKED_VAL;
            }
        }
    }
}

// ---------------------------------------------------------------------------
// statsc: per-row max and 1/sum(exp) over compacted cols (< rup(kc,64)).
// ---------------------------------------------------------------------------
__global__ __launch_bounds__(256) void statsc_kernel(
    const float* __restrict__ e, const int* __restrict__ cnts,
    float* __restrict__ stats)
{
    const int row  = blockIdx.x * 4 + (threadIdx.x >> 6);
    const int b    = row >> 11;
    const int bound = rup(cnts[b * 2], 64);
    const int lane = threadIdx.x & 63;
    const float4* er = (const float4*)(e + (size_t)row * Ln);

    float4 v[8];
    #pragma unroll
    for (int i = 0; i < 8; ++i) {
        int fidx = i * 256 + lane * 4;
        if (fidx < bound) v[i] = er[i * 64 + lane];
        else v[i] = make_float4(MASKED_VAL, MASKED_VAL, MASKED_VAL, MASKED_VAL);
    }

    float mx = -3.0e38f;
    #pragma unroll
    for (int i = 0; i < 8; ++i)
        mx = fmaxf(mx, fmaxf(fmaxf(v[i].x, v[i].y), fmaxf(v[i].z, v[i].w)));
    #pragma unroll
    for (int o = 32; o > 0; o >>= 1) mx = fmaxf(mx, __shfl_xor(mx, o, 64));

    float s = 0.f;
    #pragma unroll
    for (int i = 0; i < 8; ++i)
        s += __expf(v[i].x - mx) + __expf(v[i].y - mx) +
             __expf(v[i].z - mx) + __expf(v[i].w - mx);
    #pragma unroll
    for (int o = 32; o > 0; o >>= 1) s += __shfl_xor(s, o, 64);

    if (lane == 0) {
        stats[row * 2]     = mx;
        stats[row * 2 + 1] = 1.0f / s;
    }
}

// ---------------------------------------------------------------------------
// pvc: a[qidx[i], :] = P(compact) @ Vtc^T over compacted k; rows q-compacted.
// XCD-chunked 1D grid (1024): each XCD owns one batch.
// ---------------------------------------------------------------------------
__global__ __launch_bounds__(256) void pvc_kernel(
    const float* __restrict__ e, const u16* __restrict__ Vtc,
    const float* __restrict__ stats, const int* __restrict__ qidx,
    const int* __restrict__ cnts, float* __restrict__ out_a)
{
    __shared__ __align__(16) unsigned char As[128 * 128];
    __shared__ __align__(16) unsigned char Bs[128 * 128];

    // swizzle: nwg = 1024 = 8 * 128
    const int d = blockIdx.x;
    const int f = (d & 7) * 128 + (d >> 3);
    const int b = f >> 7;
    const int rem = f & 127;
    const int m0 = (rem >> 3) * 128;  // 16 compacted q tiles
    const int n0 = (rem & 7) * 128;   // 8 d tiles

    const int kc_b = cnts[b * 2], qc_b = cnts[b * 2 + 1];
    if (m0 >= rup(qc_b, 128)) return;
    const int kbound = rup(kc_b, 64);
    const int tid = threadIdx.x, lane = tid & 63, wid = tid >> 6;
    const int wm = (wid >> 1) * 64, wn = (wid & 1) * 64;

    const float* e_b   = e   + (size_t)b * Ln * Ln;
    const u16*   Vtc_b = Vtc + (size_t)b * Dn * Ln;
    const int*   qidx_b = qidx + b * Ln;

    const int srow = tid >> 1, half = tid & 1;
    const int grow = qidx_b[m0 + srow];
    const float* srcE = e_b + (size_t)grow * Ln + half * 32;
    const float smx  = stats[(b * Ln + grow) * 2];
    const float sinv = stats[(b * Ln + grow) * 2 + 1];
    unsigned char* wA = As + srow * 128;
    int sl[4];
    #pragma unroll
    for (int c = 0; c < 4; ++c) sl[c] = (((half * 4 + c) ^ (srow & 7)) << 4);

    const u16* gB[4];
    #pragma unroll
    for (int q = 0; q < 4; ++q) {
        int c = wid * 4 + q;
        int row = c * 8 + (lane >> 3);
        int sig = (lane & 7) ^ (row & 7);
        gB[q] = Vtc_b + (size_t)(n0 + row) * Ln + sig * 8;
    }

    f32x4 acc[4][4];
    const f32x4 z4 = {0.f, 0.f, 0.f, 0.f};
    #pragma unroll
    for (int i = 0; i < 4; ++i)
        #pragma unroll
        for (int j = 0; j < 4; ++j) acc[i][j] = z4;

    for (int k0 = 0; k0 < kbound; k0 += 64) {
        #pragma unroll
        for (int q = 0; q < 4; ++q) {
            gload16(gB[q], Bs + (wid * 4 + q) * 1024);
            gB[q] += 64;
        }
        float fe[32];
        #pragma unroll
        for (int c = 0; c < 8; ++c) *(float4*)&fe[c * 4] = *(const float4*)(srcE + c * 4);
        srcE += 64;
        #pragma unroll
        for (int c = 0; c < 4; ++c) {
            u32 p0 = pack2(__expf(fe[c*8+0] - smx) * sinv, __expf(fe[c*8+1] - smx) * sinv);
            u32 p1 = pack2(__expf(fe[c*8+2] - smx) * sinv, __expf(fe[c*8+3] - smx) * sinv);
            u32 p2 = pack2(__expf(fe[c*8+4] - smx) * sinv, __expf(fe[c*8+5] - smx) * sinv);
            u32 p3 = pack2(__expf(fe[c*8+6] - smx) * sinv, __expf(fe[c*8+7] - smx) * sinv);
            *(uint4*)(wA + sl[c]) = make_uint4(p0, p1, p2, p3);
        }
        __syncthreads();

        const int sh = lane >> 4;
        #pragma unroll
        for (int s = 0; s < 2; ++s) {
            bf16x8 af[4], bv[4];
            #pragma unroll
            for (int i = 0; i < 4; ++i) {
                int row = wm + i * 16 + (lane & 15);
                af[i] = *(const bf16x8*)(As + row * 128 + (((s * 4 + sh) ^ (row & 7)) << 4));
            }
            #pragma unroll
            for (int j = 0; j < 4; ++j) {
                int row = wn + j * 16 + (lane & 15);
                bv[j] = *(const bf16x8*)(Bs + row * 128 + (((s * 4 + sh) ^ (row & 7)) << 4));
            }
            #pragma unroll
            for (int i = 0; i < 4; ++i)
                #pragma unroll
                for (int j = 0; j < 4; ++j)
                    acc[i][j] = MFMA16(af[i], bv[j], acc[i][j]);
        }
        __syncthreads();
    }

    #pragma unroll
    for (int i = 0; i < 4; ++i) {
        #pragma unroll
        for (int r = 0; r < 4; ++r) {
            int gi = m0 + wm + i * 16 + (lane >> 4) * 4 + r;
            if (gi < qc_b) {
                int gm = qidx_b[gi];
                float* orow = out_a + (size_t)(b * Ln + gm) * Dn + n0 + wn;
                #pragma unroll
                for (int j = 0; j < 4; ++j)
                    orow[j * 16 + (lane & 15)] = acc[i][j][r];
            }
        }
    }
}

// ---------------------------------------------------------------------------
// expand: in-place per-row scatter of compacted e' to full masked e.
// ---------------------------------------------------------------------------
__global__ __launch_bounds__(256) void expand_kernel(
    float* __restrict__ e, const int* __restrict__ kpos,
    const int* __restrict__ k_mask)
{
    const int row = blockIdx.x;
    const int b = row >> 11;
    const int t = threadIdx.x;
    float* er = e + (size_t)row * Ln;
    const int* kp = kpos + b * Ln;
    const int* km = k_mask + b * Ln;

    float v[8];
    #pragma unroll
    for (int j = 0; j < 8; ++j) {
        int k = t * 8 + j;
        v[j] = km[k] ? er[kp[k]] : MASKED_VAL;
    }
    __syncthreads();
    *(float4*)(er + t * 8)     = make_float4(v[0], v[1], v[2], v[3]);
    *(float4*)(er + t * 8 + 4) = make_float4(v[4], v[5], v[6], v[7]);
}

// ---------------------------------------------------------------------------
extern "C" void kernel_launch(void* const* d_in, const int* in_sizes, int n_in,
                              void* d_out, int out_size, void* d_ws, size_t ws_size,
                              hipStream_t stream)
{
    const float* Q  = (const float*)d_in[0];
    const float* K  = (const float*)d_in[1];
    const float* V  = (const float*)d_in[2];
    const float* Wq = (const float*)d_in[3];
    const float* bq = (const float*)d_in[4];
    const float* Wk = (const float*)d_in[5];
    const float* bk = (const float*)d_in[6];
    const float* Wv = (const float*)d_in[7];
    const float* bv = (const float*)d_in[8];
    const int* q_mask = (const int*)d_in[9];
    const int* k_mask = (const int*)d_in[10];

    float* out_a = (float*)d_out;                       // [B, L, D]
    float* out_e = out_a + (size_t)Bn * Ln * Dn;        // [B, L, L]

    const size_t NE = (size_t)Bn * Ln * Dn;             // 16,777,216
    const size_t NW = (size_t)Dn * Dn;                  // 1,048,576
    const int BL = Bn * Ln;                             // 16,384

    // ws layout (all in d_ws): 6*NE u16 + 4*NW u16 + small f32/int tables
    u16* Tb  = (u16*)d_ws;
    u16* Vh  = Tb + NE;
    u16* Vtc = Vh + NE;
    u16* Vbf = Vtc + NE;
    u16* Xq  = Vbf + NE;
    u16* Xk  = Xq + NE;
    u16* Wvb = Xk + NE;
    u16* Wqt = Wvb + NW;
    u16* Wkt = Wqt + NW;
    u16* Mt  = Wkt + NW;
    float* w1    = (float*)(Mt + NW);
    float* w2    = w1 + Dn;
    float* cbuf  = w2 + Dn;
    float* uarr  = cbuf + 4;
    float* varr  = uarr + BL;
    float* vc    = varr + BL;
    float* stats = vc + BL;
    int* kidx = (int*)(stats + 2 * BL);
    int* kpos = kidx + BL;
    int* qidx = kpos + BL;
    int* cnts = qidx + BL;

    dim3 blk(256);

    // 0) mask compaction tables
    prep_kernel<<<dim3(Bn), blk, 0, stream>>>(k_mask, q_mask, kidx, kpos, qidx, cnts);

    // 1) input conversions (bf16)
    convert3_kernel<<<dim3(3 * (NE / 2048)), blk, 0, stream>>>(
        Q, K, V, Xq, Xk, Vbf, (int)(NE / 2048));
    convert_single_kernel<<<dim3(NW / 2048), blk, 0, stream>>>(Wv, Wvb, (int)NW);

    // 2) weight transposes + bias-fold vectors + c
    wtrans_kernel<<<dim3(16, 16, 2), blk, 0, stream>>>(Wq, Wk, Wqt, Wkt);
    ck_kernel<<<dim3(1), dim3(64), 0, stream>>>(bq, bk, cbuf);
    wvec_kernel<<<dim3(256, 2), blk, 0, stream>>>(Wqt, Wkt, bk, bq, w1, w2);

    // 3) Mt = Wk^T Wq result transposed (M^T row-major), bf16
    mgemm_kernel<<<dim3(8, 8), blk, 0, stream>>>(Wkt, Wqt, Mt);

    // 4) T = Xq @ M (via Mt) and Vp = Vbf @ Wv^T + bv
    proj2_kernel<<<dim3(Dn / 128, BL / 128, 2), blk, 0, stream>>>(
        Xq, Vbf, Mt, Wvb, bv, Tb, Vh);

    // 5) u = Xq.w1 + c, v = Xk.w2; gather vc = v[kidx]
    rowdot_kernel<<<dim3(BL / 4, 2), blk, 0, stream>>>(Xq, Xk, w1, w2, cbuf, uarr, varr);
    vcg_kernel<<<dim3(Bn), blk, 0, stream>>>(varr, kidx, vc);

    // 6) k-compacted V transpose
    vtransc_kernel<<<dim3(Dn / 64, Ln / 64, Bn), blk, 0, stream>>>(Vh, kidx, cnts, Vtc);

    // 7) compacted scores (Tb . Xk[kidx] + u + vc) into out_e region
    scorec_kernel<<<dim3(2048), blk, 0, stream>>>(Tb, Xk, kidx, cnts, uarr, vc, out_e);

    // 8) softmax stats over compacted cols
    statsc_kernel<<<dim3(BL / 4), blk, 0, stream>>>(out_e, cnts, stats);

    // 9) zero masked-q rows of a, then compacted PV
    zeroa_kernel<<<dim3(BL), blk, 0, stream>>>((float4*)out_a, q_mask);
    pvc_kernel<<<dim3(1024), blk, 0, stream>>>(out_e, Vtc, stats, qidx, cnts, out_a);

    // 10) expand compacted e' -> full masked e (in place, per-row)
    expand_kernel<<<dim3(BL), blk, 0, stream>>>(out_e, kpos, k_mask);
}

// Round 8
// 405.458 us; speedup vs baseline: 1.2174x; 1.2174x over previous
//
#include <hip/hip_runtime.h>
#include <cstddef>
#include <cstdint>

constexpr int Bn = 8;
constexpr int Ln = 2048;
constexpr int Dn = 1024;
constexpr float MASKED_VAL = -2147483648.0f;  // -2^31

typedef unsigned short u16;
typedef unsigned int   u32;
typedef __attribute__((ext_vector_type(8))) __bf16 bf16x8;
typedef __attribute__((ext_vector_type(4))) float  f32x4;

__device__ __forceinline__ u16 f2bf(float x) {
    u32 u = __float_as_uint(x);
    u += 0x7FFFu + ((u >> 16) & 1u);
    return (u16)(u >> 16);
}
__device__ __forceinline__ float bf2f(u16 h) {
    return __uint_as_float(((u32)h) << 16);
}
__device__ __forceinline__ u32 pack2(float a, float b) {
    return (u32)f2bf(a) | ((u32)f2bf(b) << 16);
}
__device__ __forceinline__ int rup(int x, int m) { return (x + m - 1) & ~(m - 1); }

__device__ __forceinline__ void gload16(const void* g, void* l) {
    typedef const __attribute__((address_space(1))) unsigned int* gp_t;
    typedef __attribute__((address_space(3))) unsigned int* lp_t;
    __builtin_amdgcn_global_load_lds((gp_t)g, (lp_t)l, 16, 0, 0);
}

#define MFMA16(a, b, c) __builtin_amdgcn_mfma_f32_16x16x32_bf16((a), (b), (c), 0, 0, 0)

// ---------------------------------------------------------------------------
// prep: per batch, compact index lists for k_mask (kidx + inverse kpos) and
// q_mask (qidx), plus counts. kpos = -1 for masked k. Pads kidx with last
// valid index, qidx with 0.
// ---------------------------------------------------------------------------
__global__ __launch_bounds__(256) void prep_kernel(
    const int* __restrict__ k_mask, const int* __restrict__ q_mask,
    int* __restrict__ kidx, int* __restrict__ kpos,
    int* __restrict__ qidx, int* __restrict__ cnts)
{
    __shared__ int sc[256];
    __shared__ int lastv;
    const int b = blockIdx.x, t = threadIdx.x;
    for (int pass = 0; pass < 2; ++pass) {
        const int* msk = (pass ? q_mask : k_mask) + b * Ln;
        int* idx = (pass ? qidx : kidx) + b * Ln;
        int f[8], s = 0;
        #pragma unroll
        for (int j = 0; j < 8; ++j) { f[j] = (msk[t * 8 + j] != 0) ? 1 : 0; s += f[j]; }
        sc[t] = s;
        __syncthreads();
        #pragma unroll
        for (int o = 1; o < 256; o <<= 1) {
            int v = (t >= o) ? sc[t - o] : 0;
            __syncthreads();
            sc[t] += v;
            __syncthreads();
        }
        int incl = sc[t];
        int total = sc[255];
        int p = incl - s;
        #pragma unroll
        for (int j = 0; j < 8; ++j) {
            if (pass == 0) kpos[b * Ln + t * 8 + j] = f[j] ? p : -1;
            if (f[j]) { idx[p] = t * 8 + j; ++p; }
        }
        __syncthreads();
        if (t == 0) {
            cnts[b * 2 + pass] = total;
            lastv = (total > 0) ? idx[total - 1] : 0;
        }
        __syncthreads();
        int padv = (pass == 0) ? lastv : 0;
        for (int e2 = total + t; e2 < Ln; e2 += 256) idx[e2] = padv;
        __syncthreads();
    }
}

// ---------------------------------------------------------------------------
// convert3: fp32 -> bf16 for three equally-sized arrays in one launch.
// ---------------------------------------------------------------------------
__global__ __launch_bounds__(256) void convert3_kernel(
    const float* __restrict__ s0, const float* __restrict__ s1, const float* __restrict__ s2,
    u16* __restrict__ d0, u16* __restrict__ d1, u16* __restrict__ d2, int blocksPer)
{
    int id = blockIdx.x;
    int which = id / blocksPer;
    int off = id - which * blocksPer;
    const float* src = (which == 0) ? s0 : (which == 1) ? s1 : s2;
    u16* dst = (which == 0) ? d0 : (which == 1) ? d1 : d2;
    int i = (off * 256 + threadIdx.x) * 8;
    float f[8];
    *(float4*)&f[0] = *(const float4*)(src + i);
    *(float4*)&f[4] = *(const float4*)(src + i + 4);
    u32 H[4];
    #pragma unroll
    for (int j = 0; j < 4; ++j) H[j] = pack2(f[2*j], f[2*j+1]);
    *(uint4*)(dst + i) = make_uint4(H[0], H[1], H[2], H[3]);
}

__global__ __launch_bounds__(256) void convert_single_kernel(
    const float* __restrict__ src, u16* __restrict__ dh, int n)
{
    int i = (blockIdx.x * 256 + threadIdx.x) * 8;
    if (i >= n) return;
    float f[8];
    *(float4*)&f[0] = *(const float4*)(src + i);
    *(float4*)&f[4] = *(const float4*)(src + i + 4);
    u32 H[4];
    #pragma unroll
    for (int j = 0; j < 4; ++j) H[j] = pack2(f[2*j], f[2*j+1]);
    *(uint4*)(dh + i) = make_uint4(H[0], H[1], H[2], H[3]);
}

// ---------------------------------------------------------------------------
// wtrans: W (fp32 [e][d]) -> Wt (bf16 [d][e]) for Wq and Wk (z selects).
// ---------------------------------------------------------------------------
__global__ __launch_bounds__(256) void wtrans_kernel(
    const float* __restrict__ Wq, const float* __restrict__ Wk,
    u16* __restrict__ Wqt, u16* __restrict__ Wkt)
{
    __shared__ float tile[64][68];
    const float* src = blockIdx.z ? Wk : Wq;
    u16* dst = blockIdx.z ? Wkt : Wqt;
    const int e0 = blockIdx.y * 64, d0 = blockIdx.x * 64;
    const int t = threadIdx.x;
    const int r = t >> 2, cq = (t & 3) * 16;
    const float* s = src + (size_t)(e0 + r) * Dn + d0 + cq;
    #pragma unroll
    for (int i = 0; i < 4; ++i)
        *(float4*)&tile[r][cq + i * 4] = *(const float4*)(s + i * 4);
    __syncthreads();
    u32 o[8];
    #pragma unroll
    for (int i = 0; i < 8; ++i)
        o[i] = pack2(tile[cq + 2 * i][r], tile[cq + 2 * i + 1][r]);
    u16* d = dst + (size_t)(d0 + r) * Dn + e0 + cq;
    *(uint4*)(d)     = make_uint4(o[0], o[1], o[2], o[3]);
    *(uint4*)(d + 8) = make_uint4(o[4], o[5], o[6], o[7]);
}

// ---------------------------------------------------------------------------
// ck: cbuf[0] = bq . bk
// ---------------------------------------------------------------------------
__global__ __launch_bounds__(64) void ck_kernel(
    const float* __restrict__ bq, const float* __restrict__ bk, float* __restrict__ cbuf)
{
    int l = threadIdx.x;
    float s = 0.f;
    #pragma unroll
    for (int i = 0; i < 16; ++i) s += bq[l + 64 * i] * bk[l + 64 * i];
    #pragma unroll
    for (int o = 32; o; o >>= 1) s += __shfl_xor(s, o, 64);
    if (l == 0) cbuf[0] = s;
}

// ---------------------------------------------------------------------------
// wvec: w1[d] = Wqt[d,:].bk ; w2[d] = Wkt[d,:].bq   (one wave per d)
// ---------------------------------------------------------------------------
__global__ __launch_bounds__(256) void wvec_kernel(
    const u16* __restrict__ Wqt, const u16* __restrict__ Wkt,
    const float* __restrict__ bk, const float* __restrict__ bq,
    float* __restrict__ w1, float* __restrict__ w2)
{
    const int y = blockIdx.y;
    const u16* src = y ? Wkt : Wqt;
    const float* vec = y ? bq : bk;
    float* out = y ? w2 : w1;
    const int d = blockIdx.x * 4 + (threadIdx.x >> 6);
    const int l = threadIdx.x & 63;
    float s = 0.f;
    #pragma unroll
    for (int i = 0; i < 16; ++i) {
        int e = l + 64 * i;
        s += bf2f(src[(size_t)d * Dn + e]) * vec[e];
    }
    #pragma unroll
    for (int o = 32; o; o >>= 1) s += __shfl_xor(s, o, 64);
    if (l == 0) out[d] = s;
}

// ---------------------------------------------------------------------------
// rowdot: u[row] = Xq[row,:].w1 + c ; v[row] = Xk[row,:].w2  (one wave/row)
// ---------------------------------------------------------------------------
__global__ __launch_bounds__(256) void rowdot_kernel(
    const u16* __restrict__ Xq, const u16* __restrict__ Xk,
    const float* __restrict__ w1, const float* __restrict__ w2,
    const float* __restrict__ cbuf, float* __restrict__ u, float* __restrict__ v)
{
    const int y = blockIdx.y;
    const u16* x = y ? Xk : Xq;
    const float* w = y ? w2 : w1;
    float* out = y ? v : u;
    const int row = blockIdx.x * 4 + (threadIdx.x >> 6);
    const int l = threadIdx.x & 63;
    float s = 0.f;
    #pragma unroll
    for (int h = 0; h < 2; ++h) {
        const u16* xp = x + (size_t)row * Dn + h * 512 + l * 8;
        const float* wp = w + h * 512 + l * 8;
        uint4 xv = *(const uint4*)xp;
        float4 wa = *(const float4*)(wp);
        float4 wb = *(const float4*)(wp + 4);
        const u16* xs = (const u16*)&xv;
        s += bf2f(xs[0]) * wa.x + bf2f(xs[1]) * wa.y + bf2f(xs[2]) * wa.z + bf2f(xs[3]) * wa.w
           + bf2f(xs[4]) * wb.x + bf2f(xs[5]) * wb.y + bf2f(xs[6]) * wb.z + bf2f(xs[7]) * wb.w;
    }
    #pragma unroll
    for (int o = 32; o; o >>= 1) s += __shfl_xor(s, o, 64);
    if (l == 0) out[row] = s + (y ? 0.0f : cbuf[0]);
}

// ---------------------------------------------------------------------------
// vcg: vc[b,j] = v[b, kidx[b,j]]
// ---------------------------------------------------------------------------
__global__ __launch_bounds__(256) void vcg_kernel(
    const float* __restrict__ v, const int* __restrict__ kidx, float* __restrict__ vc)
{
    const int b = blockIdx.x;
    for (int j = threadIdx.x; j < Ln; j += 256)
        vc[b * Ln + j] = v[b * Ln + kidx[b * Ln + j]];
}

// ---------------------------------------------------------------------------
// zeroa: zero a-rows where q_mask==0 (pvc writes all other rows fully).
// ---------------------------------------------------------------------------
__global__ __launch_bounds__(256) void zeroa_kernel(
    float4* __restrict__ out_a, const int* __restrict__ q_mask)
{
    const int row = blockIdx.x;
    if (q_mask[row]) return;
    out_a[(size_t)row * 256 + threadIdx.x] = make_float4(0.f, 0.f, 0.f, 0.f);
}

// ---------------------------------------------------------------------------
// mgemm: Mt[d'][d] = sum_e Wkt[d',e] * Wqt[d,e]   (1024x1024x1024, bf16 out)
// ---------------------------------------------------------------------------
__global__ __launch_bounds__(256) void mgemm_kernel(
    const u16* __restrict__ Wkt, const u16* __restrict__ Wqt, u16* __restrict__ Mt)
{
    __shared__ __align__(16) unsigned char As[128 * 128];
    __shared__ __align__(16) unsigned char Bs[128 * 128];

    const int m0 = blockIdx.y * 128, n0 = blockIdx.x * 128;
    const int tid = threadIdx.x, lane = tid & 63, wid = tid >> 6;
    const int wm = (wid >> 1) * 64, wn = (wid & 1) * 64;

    const u16* gA[4]; const u16* gB[4]; int ldsOff[4];
    #pragma unroll
    for (int q = 0; q < 4; ++q) {
        int c = wid * 4 + q;
        int row = c * 8 + (lane >> 3);
        int sig = (lane & 7) ^ (row & 7);
        gA[q] = Wkt + (size_t)(m0 + row) * Dn + sig * 8;
        gB[q] = Wqt + (size_t)(n0 + row) * Dn + sig * 8;
        ldsOff[q] = c * 1024;
    }

    f32x4 acc[4][4];
    const f32x4 z4 = {0.f, 0.f, 0.f, 0.f};
    #pragma unroll
    for (int i = 0; i < 4; ++i)
        #pragma unroll
        for (int j = 0; j < 4; ++j) acc[i][j] = z4;

    for (int k0 = 0; k0 < Dn; k0 += 64) {
        #pragma unroll
        for (int q = 0; q < 4; ++q) {
            gload16(gA[q], As + ldsOff[q]);
            gload16(gB[q], Bs + ldsOff[q]);
            gA[q] += 64; gB[q] += 64;
        }
        __syncthreads();

        const int sh = lane >> 4;
        #pragma unroll
        for (int s = 0; s < 2; ++s) {
            bf16x8 af[4], bf[4];
            #pragma unroll
            for (int i = 0; i < 4; ++i) {
                int row = wm + i * 16 + (lane & 15);
                af[i] = *(const bf16x8*)(As + row * 128 + (((s * 4 + sh) ^ (row & 7)) << 4));
            }
            #pragma unroll
            for (int j = 0; j < 4; ++j) {
                int row = wn + j * 16 + (lane & 15);
                bf[j] = *(const bf16x8*)(Bs + row * 128 + (((s * 4 + sh) ^ (row & 7)) << 4));
            }
            #pragma unroll
            for (int i = 0; i < 4; ++i)
                #pragma unroll
                for (int j = 0; j < 4; ++j)
                    acc[i][j] = MFMA16(af[i], bf[j], acc[i][j]);
        }
        __syncthreads();
    }

    #pragma unroll
    for (int i = 0; i < 4; ++i) {
        #pragma unroll
        for (int r = 0; r < 4; ++r) {
            int m = m0 + wm + i * 16 + (lane >> 4) * 4 + r;
            u16* oh = Mt + (size_t)m * Dn + n0 + wn;
            #pragma unroll
            for (int j = 0; j < 4; ++j)
                oh[j * 16 + (lane & 15)] = f2bf(acc[i][j][r]);
        }
    }
}

// ---------------------------------------------------------------------------
// proj2: z=0: Tb = Xq @ Mt^T (no bias) ; z=1: Vh = Vbf @ Wvb^T + bv.
// ---------------------------------------------------------------------------
__global__ __launch_bounds__(256) void proj2_kernel(
    const u16* __restrict__ Xq, const u16* __restrict__ Vbf,
    const u16* __restrict__ Mt, const u16* __restrict__ Wvb,
    const float* __restrict__ bv, u16* __restrict__ Tb, u16* __restrict__ Vh)
{
    __shared__ __align__(16) unsigned char As[128 * 128];
    __shared__ __align__(16) unsigned char Bs[128 * 128];

    const int z = blockIdx.z;
    const u16* X = z ? Vbf : Xq;
    const u16* W = z ? Wvb : Mt;
    const float* bias = z ? bv : nullptr;
    u16* C = z ? Vh : Tb;

    const int m0 = blockIdx.y * 128, n0 = blockIdx.x * 128;
    const int tid = threadIdx.x, lane = tid & 63, wid = tid >> 6;
    const int wm = (wid >> 1) * 64, wn = (wid & 1) * 64;

    const u16* gA[4]; const u16* gB[4]; int ldsOff[4];
    #pragma unroll
    for (int q = 0; q < 4; ++q) {
        int c = wid * 4 + q;
        int row = c * 8 + (lane >> 3);
        int sig = (lane & 7) ^ (row & 7);
        gA[q] = X + (size_t)(m0 + row) * Dn + sig * 8;
        gB[q] = W + (size_t)(n0 + row) * Dn + sig * 8;
        ldsOff[q] = c * 1024;
    }

    f32x4 acc[4][4];
    const f32x4 z4 = {0.f, 0.f, 0.f, 0.f};
    #pragma unroll
    for (int i = 0; i < 4; ++i)
        #pragma unroll
        for (int j = 0; j < 4; ++j) acc[i][j] = z4;

    for (int k0 = 0; k0 < Dn; k0 += 64) {
        #pragma unroll
        for (int q = 0; q < 4; ++q) {
            gload16(gA[q], As + ldsOff[q]);
            gload16(gB[q], Bs + ldsOff[q]);
            gA[q] += 64; gB[q] += 64;
        }
        __syncthreads();

        const int sh = lane >> 4;
        #pragma unroll
        for (int s = 0; s < 2; ++s) {
            bf16x8 af[4], bf[4];
            #pragma unroll
            for (int i = 0; i < 4; ++i) {
                int row = wm + i * 16 + (lane & 15);
                af[i] = *(const bf16x8*)(As + row * 128 + (((s * 4 + sh) ^ (row & 7)) << 4));
            }
            #pragma unroll
            for (int j = 0; j < 4; ++j) {
                int row = wn + j * 16 + (lane & 15);
                bf[j] = *(const bf16x8*)(Bs + row * 128 + (((s * 4 + sh) ^ (row & 7)) << 4));
            }
            #pragma unroll
            for (int i = 0; i < 4; ++i)
                #pragma unroll
                for (int j = 0; j < 4; ++j)
                    acc[i][j] = MFMA16(af[i], bf[j], acc[i][j]);
        }
        __syncthreads();
    }

    float bv4[4];
    #pragma unroll
    for (int j = 0; j < 4; ++j)
        bv4[j] = bias ? bias[n0 + wn + j * 16 + (lane & 15)] : 0.0f;
    #pragma unroll
    for (int i = 0; i < 4; ++i) {
        #pragma unroll
        for (int r = 0; r < 4; ++r) {
            int m = m0 + wm + i * 16 + (lane >> 4) * 4 + r;
            u16* oh = C + (size_t)m * Dn + n0 + wn;
            #pragma unroll
            for (int j = 0; j < 4; ++j)
                oh[j * 16 + (lane & 15)] = f2bf(acc[i][j][r] + bv4[j]);
        }
    }
}

// ---------------------------------------------------------------------------
// vtransc: Vtc[b][d][j] = Vh[b][kidx[b][j]][d]  (k-compacted transpose)
// ---------------------------------------------------------------------------
__global__ __launch_bounds__(256) void vtransc_kernel(
    const u16* __restrict__ Vh, const int* __restrict__ kidx,
    const int* __restrict__ cnts, u16* __restrict__ Vtc)
{
    __shared__ u16 tile[64][72];
    const int b = blockIdx.z;
    const int l0 = blockIdx.y * 64, d0 = blockIdx.x * 64;
    if (l0 >= rup(cnts[b * 2], 64)) return;
    const int t = threadIdx.x;
    const int r = t >> 2, cq = (t & 3) * 16;

    const int srcrow = kidx[b * Ln + l0 + r];
    const u16* src = Vh + (size_t)(b * Ln + srcrow) * Dn + d0 + cq;
    *(uint4*)&tile[r][cq]     = *(const uint4*)(src);
    *(uint4*)&tile[r][cq + 8] = *(const uint4*)(src + 8);
    __syncthreads();

    u16 tmp[16];
    #pragma unroll
    for (int i = 0; i < 16; ++i) tmp[i] = tile[cq + i][r];
    u16* dst = Vtc + (size_t)b * Dn * Ln + (size_t)(d0 + r) * Ln + l0 + cq;
    *(uint4*)(dst)     = *(uint4*)&tmp[0];
    *(uint4*)(dst + 8) = *(uint4*)&tmp[8];
}

// ---------------------------------------------------------------------------
// scorec: Ec[b,q,j] = bf16( Tb[b,q,:].Xk[b,kidx[j],:] + u[b,q] + vc[b,j] )
// for compacted j < kc; pad cols get bf16(MASKED). XCD-chunked 1D grid (2048).
// ---------------------------------------------------------------------------
__global__ __launch_bounds__(256) void scorec_kernel(
    const u16* __restrict__ Tb, const u16* __restrict__ Xk,
    const int* __restrict__ kidx, const int* __restrict__ cnts,
    const float* __restrict__ u, const float* __restrict__ vc,
    u16* __restrict__ Ec)
{
    __shared__ __align__(16) unsigned char As[128 * 128];
    __shared__ __align__(16) unsigned char Bs[128 * 128];

    // swizzle: nwg = 2048 = 8 * 256
    const int d = blockIdx.x;
    const int f = (d & 7) * 256 + (d >> 3);
    const int b = f >> 8;
    const int rem = f & 255;
    const int m0 = (rem >> 4) * 128;  // 16 q-tiles
    const int n0 = (rem & 15) * 128;  // 16 k-tiles

    const int kc_b = cnts[b * 2];
    if (n0 >= kc_b) return;
    const int tid = threadIdx.x, lane = tid & 63, wid = tid >> 6;
    const int wm = (wid >> 1) * 64, wn = (wid & 1) * 64;

    const size_t boff = (size_t)b * Ln * Dn;
    const u16* Tb_b = Tb + boff;
    const u16* Xk_b = Xk + boff;
    const int* kidx_b = kidx + b * Ln;

    const u16* gA[4]; const u16* gB[4]; int ldsOff[4];
    #pragma unroll
    for (int q = 0; q < 4; ++q) {
        int c = wid * 4 + q;
        int row = c * 8 + (lane >> 3);
        int sig = (lane & 7) ^ (row & 7);
        int grow = kidx_b[n0 + row];
        gA[q] = Tb_b + (size_t)(m0 + row) * Dn + sig * 8;
        gB[q] = Xk_b + (size_t)grow * Dn + sig * 8;
        ldsOff[q] = c * 1024;
    }

    f32x4 acc[4][4];
    const f32x4 z4 = {0.f, 0.f, 0.f, 0.f};
    #pragma unroll
    for (int i = 0; i < 4; ++i)
        #pragma unroll
        for (int j = 0; j < 4; ++j) acc[i][j] = z4;

    for (int k0 = 0; k0 < Dn; k0 += 64) {
        #pragma unroll
        for (int q = 0; q < 4; ++q) {
            gload16(gA[q], As + ldsOff[q]);
            gload16(gB[q], Bs + ldsOff[q]);
            gA[q] += 64; gB[q] += 64;
        }
        __syncthreads();

        const int sh = lane >> 4;
        #pragma unroll
        for (int s = 0; s < 2; ++s) {
            bf16x8 af[4], bf[4];
            #pragma unroll
            for (int i = 0; i < 4; ++i) {
                int row = wm + i * 16 + (lane & 15);
                af[i] = *(const bf16x8*)(As + row * 128 + (((s * 4 + sh) ^ (row & 7)) << 4));
            }
            #pragma unroll
            for (int j = 0; j < 4; ++j) {
                int row = wn + j * 16 + (lane & 15);
                bf[j] = *(const bf16x8*)(Bs + row * 128 + (((s * 4 + sh) ^ (row & 7)) << 4));
            }
            #pragma unroll
            for (int i = 0; i < 4; ++i)
                #pragma unroll
                for (int j = 0; j < 4; ++j)
                    acc[i][j] = MFMA16(af[i], bf[j], acc[i][j]);
        }
        __syncthreads();
    }

    float vcl[4];
    #pragma unroll
    for (int j = 0; j < 4; ++j) vcl[j] = vc[b * Ln + n0 + wn + j * 16 + (lane & 15)];
    #pragma unroll
    for (int i = 0; i < 4; ++i) {
        #pragma unroll
        for (int r = 0; r < 4; ++r) {
            int m = m0 + wm + i * 16 + (lane >> 4) * 4 + r;
            float um = u[b * Ln + m];
            u16* orow = Ec + ((size_t)(b * Ln + m)) * Ln + n0 + wn;
            #pragma unroll
            for (int j = 0; j < 4; ++j) {
                int jj = n0 + wn + j * 16 + (lane & 15);
                orow[j * 16 + (lane & 15)] =
                    f2bf((jj < kc_b) ? (acc[i][j][r] + um + vcl[j]) : MASKED_VAL);
            }
        }
    }
}

// ---------------------------------------------------------------------------
// statsc: per-row max and 1/sum(exp) over compacted cols (< rup(kc,64)),
// reading bf16 Ec.
// ---------------------------------------------------------------------------
__global__ __launch_bounds__(256) void statsc_kernel(
    const u16* __restrict__ Ec, const int* __restrict__ cnts,
    float* __restrict__ stats)
{
    const int row  = blockIdx.x * 4 + (threadIdx.x >> 6);
    const int b    = row >> 11;
    const int bound = rup(cnts[b * 2], 64);
    const int lane = threadIdx.x & 63;
    const u16* er = Ec + (size_t)row * Ln;

    float v[32];
    #pragma unroll
    for (int i = 0; i < 4; ++i) {
        int fidx = i * 512 + lane * 8;
        if (fidx < bound) {
            uint4 x = *(const uint4*)(er + fidx);
            const u16* xs = (const u16*)&x;
            #pragma unroll
            for (int j = 0; j < 8; ++j) v[i * 8 + j] = bf2f(xs[j]);
        } else {
            #pragma unroll
            for (int j = 0; j < 8; ++j) v[i * 8 + j] = MASKED_VAL;
        }
    }

    float mx = -3.0e38f;
    #pragma unroll
    for (int i = 0; i < 32; ++i) mx = fmaxf(mx, v[i]);
    #pragma unroll
    for (int o = 32; o > 0; o >>= 1) mx = fmaxf(mx, __shfl_xor(mx, o, 64));

    float s = 0.f;
    #pragma unroll
    for (int i = 0; i < 32; ++i) s += __expf(v[i] - mx);
    #pragma unroll
    for (int o = 32; o > 0; o >>= 1) s += __shfl_xor(s, o, 64);

    if (lane == 0) {
        stats[row * 2]     = mx;
        stats[row * 2 + 1] = 1.0f / s;
    }
}

// ---------------------------------------------------------------------------
// pvc: a[qidx[i], :] = P(compact) @ Vtc^T over compacted k; rows q-compacted.
// P built from bf16 Ec. XCD-chunked 1D grid (1024).
// ---------------------------------------------------------------------------
__global__ __launch_bounds__(256) void pvc_kernel(
    const u16* __restrict__ Ec, const u16* __restrict__ Vtc,
    const float* __restrict__ stats, const int* __restrict__ qidx,
    const int* __restrict__ cnts, float* __restrict__ out_a)
{
    __shared__ __align__(16) unsigned char As[128 * 128];
    __shared__ __align__(16) unsigned char Bs[128 * 128];

    // swizzle: nwg = 1024 = 8 * 128
    const int d = blockIdx.x;
    const int f = (d & 7) * 128 + (d >> 3);
    const int b = f >> 7;
    const int rem = f & 127;
    const int m0 = (rem >> 3) * 128;  // 16 compacted q tiles
    const int n0 = (rem & 7) * 128;   // 8 d tiles

    const int kc_b = cnts[b * 2], qc_b = cnts[b * 2 + 1];
    if (m0 >= rup(qc_b, 128)) return;
    const int kbound = rup(kc_b, 64);
    const int tid = threadIdx.x, lane = tid & 63, wid = tid >> 6;
    const int wm = (wid >> 1) * 64, wn = (wid & 1) * 64;

    const u16* Ec_b  = Ec  + (size_t)b * Ln * Ln;
    const u16* Vtc_b = Vtc + (size_t)b * Dn * Ln;
    const int* qidx_b = qidx + b * Ln;

    const int srow = tid >> 1, half = tid & 1;
    const int grow = qidx_b[m0 + srow];
    const u16* srcP = Ec_b + (size_t)grow * Ln + half * 32;
    const float smx  = stats[(b * Ln + grow) * 2];
    const float sinv = stats[(b * Ln + grow) * 2 + 1];
    unsigned char* wA = As + srow * 128;
    int sl[4];
    #pragma unroll
    for (int c = 0; c < 4; ++c) sl[c] = (((half * 4 + c) ^ (srow & 7)) << 4);

    const u16* gB[4];
    #pragma unroll
    for (int q = 0; q < 4; ++q) {
        int c = wid * 4 + q;
        int row = c * 8 + (lane >> 3);
        int sig = (lane & 7) ^ (row & 7);
        gB[q] = Vtc_b + (size_t)(n0 + row) * Ln + sig * 8;
    }

    f32x4 acc[4][4];
    const f32x4 z4 = {0.f, 0.f, 0.f, 0.f};
    #pragma unroll
    for (int i = 0; i < 4; ++i)
        #pragma unroll
        for (int j = 0; j < 4; ++j) acc[i][j] = z4;

    for (int k0 = 0; k0 < kbound; k0 += 64) {
        #pragma unroll
        for (int q = 0; q < 4; ++q) {
            gload16(gB[q], Bs + (wid * 4 + q) * 1024);
            gB[q] += 64;
        }
        u16 tmp[32];
        *(uint4*)&tmp[0]  = *(const uint4*)(srcP);
        *(uint4*)&tmp[8]  = *(const uint4*)(srcP + 8);
        *(uint4*)&tmp[16] = *(const uint4*)(srcP + 16);
        *(uint4*)&tmp[24] = *(const uint4*)(srcP + 24);
        srcP += 64;
        float fe[32];
        #pragma unroll
        for (int j = 0; j < 32; ++j) fe[j] = bf2f(tmp[j]);
        #pragma unroll
        for (int c = 0; c < 4; ++c) {
            u32 p0 = pack2(__expf(fe[c*8+0] - smx) * sinv, __expf(fe[c*8+1] - smx) * sinv);
            u32 p1 = pack2(__expf(fe[c*8+2] - smx) * sinv, __expf(fe[c*8+3] - smx) * sinv);
            u32 p2 = pack2(__expf(fe[c*8+4] - smx) * sinv, __expf(fe[c*8+5] - smx) * sinv);
            u32 p3 = pack2(__expf(fe[c*8+6] - smx) * sinv, __expf(fe[c*8+7] - smx) * sinv);
            *(uint4*)(wA + sl[c]) = make_uint4(p0, p1, p2, p3);
        }
        __syncthreads();

        const int sh = lane >> 4;
        #pragma unroll
        for (int s = 0; s < 2; ++s) {
            bf16x8 af[4], bv[4];
            #pragma unroll
            for (int i = 0; i < 4; ++i) {
                int row = wm + i * 16 + (lane & 15);
                af[i] = *(const bf16x8*)(As + row * 128 + (((s * 4 + sh) ^ (row & 7)) << 4));
            }
            #pragma unroll
            for (int j = 0; j < 4; ++j) {
                int row = wn + j * 16 + (lane & 15);
                bv[j] = *(const bf16x8*)(Bs + row * 128 + (((s * 4 + sh) ^ (row & 7)) << 4));
            }
            #pragma unroll
            for (int i = 0; i < 4; ++i)
                #pragma unroll
                for (int j = 0; j < 4; ++j)
                    acc[i][j] = MFMA16(af[i], bv[j], acc[i][j]);
        }
        __syncthreads();
    }

    #pragma unroll
    for (int i = 0; i < 4; ++i) {
        #pragma unroll
        for (int r = 0; r < 4; ++r) {
            int gi = m0 + wm + i * 16 + (lane >> 4) * 4 + r;
            if (gi < qc_b) {
                int gm = qidx_b[gi];
                float* orow = out_a + (size_t)(b * Ln + gm) * Dn + n0 + wn;
                #pragma unroll
                for (int j = 0; j < 4; ++j)
                    orow[j * 16 + (lane & 15)] = acc[i][j][r];
            }
        }
    }
}

// ---------------------------------------------------------------------------
// expand: out-of-place scatter of compacted bf16 Ec to full masked f32 e.
// Barrier-free streaming: kpos[k] >= 0 selects the compacted source column.
// ---------------------------------------------------------------------------
__global__ __launch_bounds__(256) void expand_kernel(
    const u16* __restrict__ Ec, const int* __restrict__ kpos,
    float* __restrict__ e)
{
    const int row = blockIdx.x;
    const int b = row >> 11;
    const int t = threadIdx.x;
    const u16* src = Ec + (size_t)row * Ln;
    const int* kp = kpos + b * Ln;
    const int k = t * 8;

    int p[8];
    *(int4*)&p[0] = *(const int4*)(kp + k);
    *(int4*)&p[4] = *(const int4*)(kp + k + 4);
    float v[8];
    #pragma unroll
    for (int j = 0; j < 8; ++j)
        v[j] = (p[j] >= 0) ? bf2f(src[p[j]]) : MASKED_VAL;

    float* er = e + (size_t)row * Ln + k;
    *(float4*)(er)     = make_float4(v[0], v[1], v[2], v[3]);
    *(float4*)(er + 4) = make_float4(v[4], v[5], v[6], v[7]);
}

// ---------------------------------------------------------------------------
extern "C" void kernel_launch(void* const* d_in, const int* in_sizes, int n_in,
                              void* d_out, int out_size, void* d_ws, size_t ws_size,
                              hipStream_t stream)
{
    const float* Q  = (const float*)d_in[0];
    const float* K  = (const float*)d_in[1];
    const float* V  = (const float*)d_in[2];
    const float* Wq = (const float*)d_in[3];
    const float* bq = (const float*)d_in[4];
    const float* Wk = (const float*)d_in[5];
    const float* bk = (const float*)d_in[6];
    const float* Wv = (const float*)d_in[7];
    const float* bv = (const float*)d_in[8];
    const int* q_mask = (const int*)d_in[9];
    const int* k_mask = (const int*)d_in[10];

    float* out_a = (float*)d_out;                       // [B, L, D]
    float* out_e = out_a + (size_t)Bn * Ln * Dn;        // [B, L, L]

    const size_t NE = (size_t)Bn * Ln * Dn;             // 16,777,216
    const size_t NW = (size_t)Dn * Dn;                  // 1,048,576
    const int BL = Bn * Ln;                             // 16,384

    // ws layout: Tb Vh Vtc [Vbf Xq -> Ec alias] Xk Wvb Wqt Wkt Mt + tables
    u16* Tb  = (u16*)d_ws;
    u16* Vh  = Tb + NE;
    u16* Vtc = Vh + NE;
    u16* Vbf = Vtc + NE;
    u16* Xq  = Vbf + NE;
    u16* Xk  = Xq + NE;
    u16* Wvb = Xk + NE;
    u16* Wqt = Wvb + NW;
    u16* Wkt = Wqt + NW;
    u16* Mt  = Wkt + NW;
    float* w1    = (float*)(Mt + NW);
    float* w2    = w1 + Dn;
    float* cbuf  = w2 + Dn;
    float* uarr  = cbuf + 4;
    float* varr  = uarr + BL;
    float* vc    = varr + BL;
    float* stats = vc + BL;
    int* kidx = (int*)(stats + 2 * BL);
    int* kpos = kidx + BL;
    int* qidx = kpos + BL;
    int* cnts = qidx + BL;

    // Ec (bf16 e', [B][L][Ln] u16 = 2*NE u16) aliases Vbf+Xq, both dead
    // after proj2/rowdot and before scorec.
    u16* Ec = Vbf;

    dim3 blk(256);

    // 0) mask compaction tables
    prep_kernel<<<dim3(Bn), blk, 0, stream>>>(k_mask, q_mask, kidx, kpos, qidx, cnts);

    // 1) input conversions (bf16)
    convert3_kernel<<<dim3(3 * (NE / 2048)), blk, 0, stream>>>(
        Q, K, V, Xq, Xk, Vbf, (int)(NE / 2048));
    convert_single_kernel<<<dim3(NW / 2048), blk, 0, stream>>>(Wv, Wvb, (int)NW);

    // 2) weight transposes + bias-fold vectors + c
    wtrans_kernel<<<dim3(16, 16, 2), blk, 0, stream>>>(Wq, Wk, Wqt, Wkt);
    ck_kernel<<<dim3(1), dim3(64), 0, stream>>>(bq, bk, cbuf);
    wvec_kernel<<<dim3(256, 2), blk, 0, stream>>>(Wqt, Wkt, bk, bq, w1, w2);

    // 3) Mt = Wk^T Wq (transposed result), bf16
    mgemm_kernel<<<dim3(8, 8), blk, 0, stream>>>(Wkt, Wqt, Mt);

    // 4) T = Xq @ M (via Mt) and Vp = Vbf @ Wv^T + bv
    proj2_kernel<<<dim3(Dn / 128, BL / 128, 2), blk, 0, stream>>>(
        Xq, Vbf, Mt, Wvb, bv, Tb, Vh);

    // 5) u = Xq.w1 + c, v = Xk.w2; gather vc = v[kidx]  (Xq dead after this)
    rowdot_kernel<<<dim3(BL / 4, 2), blk, 0, stream>>>(Xq, Xk, w1, w2, cbuf, uarr, varr);
    vcg_kernel<<<dim3(Bn), blk, 0, stream>>>(varr, kidx, vc);

    // 6) k-compacted V transpose
    vtransc_kernel<<<dim3(Dn / 64, Ln / 64, Bn), blk, 0, stream>>>(Vh, kidx, cnts, Vtc);

    // 7) compacted scores -> bf16 Ec (overwrites dead Vbf/Xq)
    scorec_kernel<<<dim3(2048), blk, 0, stream>>>(Tb, Xk, kidx, cnts, uarr, vc, Ec);

    // 8) softmax stats over compacted cols (bf16 read)
    statsc_kernel<<<dim3(BL / 4), blk, 0, stream>>>(Ec, cnts, stats);

    // 9) zero masked-q rows of a, then compacted PV (bf16 P source)
    zeroa_kernel<<<dim3(BL), blk, 0, stream>>>((float4*)out_a, q_mask);
    pvc_kernel<<<dim3(1024), blk, 0, stream>>>(Ec, Vtc, stats, qidx, cnts, out_a);

    // 10) expand bf16 Ec -> full masked f32 e (out-of-place, barrier-free)
    expand_kernel<<<dim3(BL), blk, 0, stream>>>(Ec, kpos, out_e);
}

// Round 9
// 393.803 us; speedup vs baseline: 1.2534x; 1.0296x over previous
//
#include <hip/hip_runtime.h>
#include <cstddef>
#include <cstdint>

constexpr int Bn = 8;
constexpr int Ln = 2048;
constexpr int Dn = 1024;
constexpr float MASKED_VAL = -2147483648.0f;  // -2^31

typedef unsigned short u16;
typedef unsigned int   u32;
typedef __attribute__((ext_vector_type(8))) __bf16 bf16x8;
typedef __attribute__((ext_vector_type(4))) float  f32x4;

__device__ __forceinline__ u16 f2bf(float x) {
    u32 u = __float_as_uint(x);
    u += 0x7FFFu + ((u >> 16) & 1u);
    return (u16)(u >> 16);
}
__device__ __forceinline__ float bf2f(u16 h) {
    return __uint_as_float(((u32)h) << 16);
}
__device__ __forceinline__ u32 pack2(float a, float b) {
    return (u32)f2bf(a) | ((u32)f2bf(b) << 16);
}
__device__ __forceinline__ int rup(int x, int m) { return (x + m - 1) & ~(m - 1); }

__device__ __forceinline__ void gload16(const void* g, void* l) {
    typedef const __attribute__((address_space(1))) unsigned int* gp_t;
    typedef __attribute__((address_space(3))) unsigned int* lp_t;
    __builtin_amdgcn_global_load_lds((gp_t)g, (lp_t)l, 16, 0, 0);
}

#define MFMA16(a, b, c) __builtin_amdgcn_mfma_f32_16x16x32_bf16((a), (b), (c), 0, 0, 0)

// ---------------------------------------------------------------------------
// prep: per batch, compact index lists for k_mask (kidx + inverse kpos) and
// q_mask (qidx), plus counts. kpos = -1 for masked k. Pads kidx with last
// valid index, qidx with 0.
// ---------------------------------------------------------------------------
__global__ __launch_bounds__(256) void prep_kernel(
    const int* __restrict__ k_mask, const int* __restrict__ q_mask,
    int* __restrict__ kidx, int* __restrict__ kpos,
    int* __restrict__ qidx, int* __restrict__ cnts)
{
    __shared__ int sc[256];
    __shared__ int lastv;
    const int b = blockIdx.x, t = threadIdx.x;
    for (int pass = 0; pass < 2; ++pass) {
        const int* msk = (pass ? q_mask : k_mask) + b * Ln;
        int* idx = (pass ? qidx : kidx) + b * Ln;
        int f[8], s = 0;
        #pragma unroll
        for (int j = 0; j < 8; ++j) { f[j] = (msk[t * 8 + j] != 0) ? 1 : 0; s += f[j]; }
        sc[t] = s;
        __syncthreads();
        #pragma unroll
        for (int o = 1; o < 256; o <<= 1) {
            int v = (t >= o) ? sc[t - o] : 0;
            __syncthreads();
            sc[t] += v;
            __syncthreads();
        }
        int incl = sc[t];
        int total = sc[255];
        int p = incl - s;
        #pragma unroll
        for (int j = 0; j < 8; ++j) {
            if (pass == 0) kpos[b * Ln + t * 8 + j] = f[j] ? p : -1;
            if (f[j]) { idx[p] = t * 8 + j; ++p; }
        }
        __syncthreads();
        if (t == 0) {
            cnts[b * 2 + pass] = total;
            lastv = (total > 0) ? idx[total - 1] : 0;
        }
        __syncthreads();
        int padv = (pass == 0) ? lastv : 0;
        for (int e2 = total + t; e2 < Ln; e2 += 256) idx[e2] = padv;
        __syncthreads();
    }
}

// ---------------------------------------------------------------------------
// convert3: fp32 -> bf16 for three equally-sized arrays in one launch.
// ---------------------------------------------------------------------------
__global__ __launch_bounds__(256) void convert3_kernel(
    const float* __restrict__ s0, const float* __restrict__ s1, const float* __restrict__ s2,
    u16* __restrict__ d0, u16* __restrict__ d1, u16* __restrict__ d2, int blocksPer)
{
    int id = blockIdx.x;
    int which = id / blocksPer;
    int off = id - which * blocksPer;
    const float* src = (which == 0) ? s0 : (which == 1) ? s1 : s2;
    u16* dst = (which == 0) ? d0 : (which == 1) ? d1 : d2;
    int i = (off * 256 + threadIdx.x) * 8;
    float f[8];
    *(float4*)&f[0] = *(const float4*)(src + i);
    *(float4*)&f[4] = *(const float4*)(src + i + 4);
    u32 H[4];
    #pragma unroll
    for (int j = 0; j < 4; ++j) H[j] = pack2(f[2*j], f[2*j+1]);
    *(uint4*)(dst + i) = make_uint4(H[0], H[1], H[2], H[3]);
}

__global__ __launch_bounds__(256) void convert_single_kernel(
    const float* __restrict__ src, u16* __restrict__ dh, int n)
{
    int i = (blockIdx.x * 256 + threadIdx.x) * 8;
    if (i >= n) return;
    float f[8];
    *(float4*)&f[0] = *(const float4*)(src + i);
    *(float4*)&f[4] = *(const float4*)(src + i + 4);
    u32 H[4];
    #pragma unroll
    for (int j = 0; j < 4; ++j) H[j] = pack2(f[2*j], f[2*j+1]);
    *(uint4*)(dh + i) = make_uint4(H[0], H[1], H[2], H[3]);
}

// ---------------------------------------------------------------------------
// wtrans: W (fp32 [e][d]) -> Wt (bf16 [d][e]) for Wq and Wk (z selects).
// ---------------------------------------------------------------------------
__global__ __launch_bounds__(256) void wtrans_kernel(
    const float* __restrict__ Wq, const float* __restrict__ Wk,
    u16* __restrict__ Wqt, u16* __restrict__ Wkt)
{
    __shared__ float tile[64][68];
    const float* src = blockIdx.z ? Wk : Wq;
    u16* dst = blockIdx.z ? Wkt : Wqt;
    const int e0 = blockIdx.y * 64, d0 = blockIdx.x * 64;
    const int t = threadIdx.x;
    const int r = t >> 2, cq = (t & 3) * 16;
    const float* s = src + (size_t)(e0 + r) * Dn + d0 + cq;
    #pragma unroll
    for (int i = 0; i < 4; ++i)
        *(float4*)&tile[r][cq + i * 4] = *(const float4*)(s + i * 4);
    __syncthreads();
    u32 o[8];
    #pragma unroll
    for (int i = 0; i < 8; ++i)
        o[i] = pack2(tile[cq + 2 * i][r], tile[cq + 2 * i + 1][r]);
    u16* d = dst + (size_t)(d0 + r) * Dn + e0 + cq;
    *(uint4*)(d)     = make_uint4(o[0], o[1], o[2], o[3]);
    *(uint4*)(d + 8) = make_uint4(o[4], o[5], o[6], o[7]);
}

// ---------------------------------------------------------------------------
// ck: cbuf[0] = bq . bk
// ---------------------------------------------------------------------------
__global__ __launch_bounds__(64) void ck_kernel(
    const float* __restrict__ bq, const float* __restrict__ bk, float* __restrict__ cbuf)
{
    int l = threadIdx.x;
    float s = 0.f;
    #pragma unroll
    for (int i = 0; i < 16; ++i) s += bq[l + 64 * i] * bk[l + 64 * i];
    #pragma unroll
    for (int o = 32; o; o >>= 1) s += __shfl_xor(s, o, 64);
    if (l == 0) cbuf[0] = s;
}

// ---------------------------------------------------------------------------
// wvec: w1[d] = Wqt[d,:].bk ; w2[d] = Wkt[d,:].bq   (one wave per d)
// ---------------------------------------------------------------------------
__global__ __launch_bounds__(256) void wvec_kernel(
    const u16* __restrict__ Wqt, const u16* __restrict__ Wkt,
    const float* __restrict__ bk, const float* __restrict__ bq,
    float* __restrict__ w1, float* __restrict__ w2)
{
    const int y = blockIdx.y;
    const u16* src = y ? Wkt : Wqt;
    const float* vec = y ? bq : bk;
    float* out = y ? w2 : w1;
    const int d = blockIdx.x * 4 + (threadIdx.x >> 6);
    const int l = threadIdx.x & 63;
    float s = 0.f;
    #pragma unroll
    for (int i = 0; i < 16; ++i) {
        int e = l + 64 * i;
        s += bf2f(src[(size_t)d * Dn + e]) * vec[e];
    }
    #pragma unroll
    for (int o = 32; o; o >>= 1) s += __shfl_xor(s, o, 64);
    if (l == 0) out[d] = s;
}

// ---------------------------------------------------------------------------
// rowdot: u[row] = Xq[row,:].w1 + c ; v[row] = Xk[row,:].w2  (one wave/row)
// ---------------------------------------------------------------------------
__global__ __launch_bounds__(256) void rowdot_kernel(
    const u16* __restrict__ Xq, const u16* __restrict__ Xk,
    const float* __restrict__ w1, const float* __restrict__ w2,
    const float* __restrict__ cbuf, float* __restrict__ u, float* __restrict__ v)
{
    const int y = blockIdx.y;
    const u16* x = y ? Xk : Xq;
    const float* w = y ? w2 : w1;
    float* out = y ? v : u;
    const int row = blockIdx.x * 4 + (threadIdx.x >> 6);
    const int l = threadIdx.x & 63;
    float s = 0.f;
    #pragma unroll
    for (int h = 0; h < 2; ++h) {
        const u16* xp = x + (size_t)row * Dn + h * 512 + l * 8;
        const float* wp = w + h * 512 + l * 8;
        uint4 xv = *(const uint4*)xp;
        float4 wa = *(const float4*)(wp);
        float4 wb = *(const float4*)(wp + 4);
        const u16* xs = (const u16*)&xv;
        s += bf2f(xs[0]) * wa.x + bf2f(xs[1]) * wa.y + bf2f(xs[2]) * wa.z + bf2f(xs[3]) * wa.w
           + bf2f(xs[4]) * wb.x + bf2f(xs[5]) * wb.y + bf2f(xs[6]) * wb.z + bf2f(xs[7]) * wb.w;
    }
    #pragma unroll
    for (int o = 32; o; o >>= 1) s += __shfl_xor(s, o, 64);
    if (l == 0) out[row] = s + (y ? 0.0f : cbuf[0]);
}

// ---------------------------------------------------------------------------
// vcg: vc[b,j] = v[b, kidx[b,j]]
// ---------------------------------------------------------------------------
__global__ __launch_bounds__(256) void vcg_kernel(
    const float* __restrict__ v, const int* __restrict__ kidx, float* __restrict__ vc)
{
    const int b = blockIdx.x;
    for (int j = threadIdx.x; j < Ln; j += 256)
        vc[b * Ln + j] = v[b * Ln + kidx[b * Ln + j]];
}

// ---------------------------------------------------------------------------
// zeroa: zero a-rows where q_mask==0 (pvc writes all other rows fully).
// ---------------------------------------------------------------------------
__global__ __launch_bounds__(256) void zeroa_kernel(
    float4* __restrict__ out_a, const int* __restrict__ q_mask)
{
    const int row = blockIdx.x;
    if (q_mask[row]) return;
    out_a[(size_t)row * 256 + threadIdx.x] = make_float4(0.f, 0.f, 0.f, 0.f);
}

// ---------------------------------------------------------------------------
// mgemm: Mt[d'][d] = sum_e Wkt[d',e] * Wqt[d,e]   (1024x1024x1024, bf16 out)
// ---------------------------------------------------------------------------
__global__ __launch_bounds__(256) void mgemm_kernel(
    const u16* __restrict__ Wkt, const u16* __restrict__ Wqt, u16* __restrict__ Mt)
{
    __shared__ __align__(16) unsigned char As[128 * 128];
    __shared__ __align__(16) unsigned char Bs[128 * 128];

    const int m0 = blockIdx.y * 128, n0 = blockIdx.x * 128;
    const int tid = threadIdx.x, lane = tid & 63, wid = tid >> 6;
    const int wm = (wid >> 1) * 64, wn = (wid & 1) * 64;

    const u16* gA[4]; const u16* gB[4]; int ldsOff[4];
    #pragma unroll
    for (int q = 0; q < 4; ++q) {
        int c = wid * 4 + q;
        int row = c * 8 + (lane >> 3);
        int sig = (lane & 7) ^ (row & 7);
        gA[q] = Wkt + (size_t)(m0 + row) * Dn + sig * 8;
        gB[q] = Wqt + (size_t)(n0 + row) * Dn + sig * 8;
        ldsOff[q] = c * 1024;
    }

    f32x4 acc[4][4];
    const f32x4 z4 = {0.f, 0.f, 0.f, 0.f};
    #pragma unroll
    for (int i = 0; i < 4; ++i)
        #pragma unroll
        for (int j = 0; j < 4; ++j) acc[i][j] = z4;

    for (int k0 = 0; k0 < Dn; k0 += 64) {
        #pragma unroll
        for (int q = 0; q < 4; ++q) {
            gload16(gA[q], As + ldsOff[q]);
            gload16(gB[q], Bs + ldsOff[q]);
            gA[q] += 64; gB[q] += 64;
        }
        __syncthreads();

        const int sh = lane >> 4;
        #pragma unroll
        for (int s = 0; s < 2; ++s) {
            bf16x8 af[4], bf[4];
            #pragma unroll
            for (int i = 0; i < 4; ++i) {
                int row = wm + i * 16 + (lane & 15);
                af[i] = *(const bf16x8*)(As + row * 128 + (((s * 4 + sh) ^ (row & 7)) << 4));
            }
            #pragma unroll
            for (int j = 0; j < 4; ++j) {
                int row = wn + j * 16 + (lane & 15);
                bf[j] = *(const bf16x8*)(Bs + row * 128 + (((s * 4 + sh) ^ (row & 7)) << 4));
            }
            #pragma unroll
            for (int i = 0; i < 4; ++i)
                #pragma unroll
                for (int j = 0; j < 4; ++j)
                    acc[i][j] = MFMA16(af[i], bf[j], acc[i][j]);
        }
        __syncthreads();
    }

    #pragma unroll
    for (int i = 0; i < 4; ++i) {
        #pragma unroll
        for (int r = 0; r < 4; ++r) {
            int m = m0 + wm + i * 16 + (lane >> 4) * 4 + r;
            u16* oh = Mt + (size_t)m * Dn + n0 + wn;
            #pragma unroll
            for (int j = 0; j < 4; ++j)
                oh[j * 16 + (lane & 15)] = f2bf(acc[i][j][r]);
        }
    }
}

// ---------------------------------------------------------------------------
// proj2: Tb = Xq @ Mt^T (no bias). Grid (Dn/128, BL/128).
// ---------------------------------------------------------------------------
__global__ __launch_bounds__(256) void proj2_kernel(
    const u16* __restrict__ Xq, const u16* __restrict__ Mt, u16* __restrict__ Tb)
{
    __shared__ __align__(16) unsigned char As[128 * 128];
    __shared__ __align__(16) unsigned char Bs[128 * 128];

    const int m0 = blockIdx.y * 128, n0 = blockIdx.x * 128;
    const int tid = threadIdx.x, lane = tid & 63, wid = tid >> 6;
    const int wm = (wid >> 1) * 64, wn = (wid & 1) * 64;

    const u16* gA[4]; const u16* gB[4]; int ldsOff[4];
    #pragma unroll
    for (int q = 0; q < 4; ++q) {
        int c = wid * 4 + q;
        int row = c * 8 + (lane >> 3);
        int sig = (lane & 7) ^ (row & 7);
        gA[q] = Xq + (size_t)(m0 + row) * Dn + sig * 8;
        gB[q] = Mt + (size_t)(n0 + row) * Dn + sig * 8;
        ldsOff[q] = c * 1024;
    }

    f32x4 acc[4][4];
    const f32x4 z4 = {0.f, 0.f, 0.f, 0.f};
    #pragma unroll
    for (int i = 0; i < 4; ++i)
        #pragma unroll
        for (int j = 0; j < 4; ++j) acc[i][j] = z4;

    for (int k0 = 0; k0 < Dn; k0 += 64) {
        #pragma unroll
        for (int q = 0; q < 4; ++q) {
            gload16(gA[q], As + ldsOff[q]);
            gload16(gB[q], Bs + ldsOff[q]);
            gA[q] += 64; gB[q] += 64;
        }
        __syncthreads();

        const int sh = lane >> 4;
        #pragma unroll
        for (int s = 0; s < 2; ++s) {
            bf16x8 af[4], bf[4];
            #pragma unroll
            for (int i = 0; i < 4; ++i) {
                int row = wm + i * 16 + (lane & 15);
                af[i] = *(const bf16x8*)(As + row * 128 + (((s * 4 + sh) ^ (row & 7)) << 4));
            }
            #pragma unroll
            for (int j = 0; j < 4; ++j) {
                int row = wn + j * 16 + (lane & 15);
                bf[j] = *(const bf16x8*)(Bs + row * 128 + (((s * 4 + sh) ^ (row & 7)) << 4));
            }
            #pragma unroll
            for (int i = 0; i < 4; ++i)
                #pragma unroll
                for (int j = 0; j < 4; ++j)
                    acc[i][j] = MFMA16(af[i], bf[j], acc[i][j]);
        }
        __syncthreads();
    }

    #pragma unroll
    for (int i = 0; i < 4; ++i) {
        #pragma unroll
        for (int r = 0; r < 4; ++r) {
            int m = m0 + wm + i * 16 + (lane >> 4) * 4 + r;
            u16* oh = Tb + (size_t)m * Dn + n0 + wn;
            #pragma unroll
            for (int j = 0; j < 4; ++j)
                oh[j * 16 + (lane & 15)] = f2bf(acc[i][j][r]);
        }
    }
}

// ---------------------------------------------------------------------------
// projv: Vhc[b][j][:] = Vbf[b][kidx[b][j]][:] @ Wvb^T + bv  for compacted j.
// Only rup(kc,128) rows per batch computed (half the work on avg masks).
// ---------------------------------------------------------------------------
__global__ __launch_bounds__(256) void projv_kernel(
    const u16* __restrict__ Vbf, const u16* __restrict__ Wvb,
    const float* __restrict__ bv, const int* __restrict__ kidx,
    const int* __restrict__ cnts, u16* __restrict__ Vhc)
{
    __shared__ __align__(16) unsigned char As[128 * 128];
    __shared__ __align__(16) unsigned char Bs[128 * 128];

    const int b = blockIdx.z;
    const int kc_b = cnts[b * 2];
    const int m0 = blockIdx.y * 128;
    if (m0 >= rup(kc_b, 128)) return;
    const int n0 = blockIdx.x * 128;
    const int tid = threadIdx.x, lane = tid & 63, wid = tid >> 6;
    const int wm = (wid >> 1) * 64, wn = (wid & 1) * 64;

    const u16* Vbf_b = Vbf + (size_t)b * Ln * Dn;
    const int* kidx_b = kidx + b * Ln;

    const u16* gA[4]; const u16* gB[4]; int ldsOff[4];
    #pragma unroll
    for (int q = 0; q < 4; ++q) {
        int c = wid * 4 + q;
        int row = c * 8 + (lane >> 3);
        int sig = (lane & 7) ^ (row & 7);
        int grow = kidx_b[m0 + row];
        gA[q] = Vbf_b + (size_t)grow * Dn + sig * 8;
        gB[q] = Wvb + (size_t)(n0 + row) * Dn + sig * 8;
        ldsOff[q] = c * 1024;
    }

    f32x4 acc[4][4];
    const f32x4 z4 = {0.f, 0.f, 0.f, 0.f};
    #pragma unroll
    for (int i = 0; i < 4; ++i)
        #pragma unroll
        for (int j = 0; j < 4; ++j) acc[i][j] = z4;

    for (int k0 = 0; k0 < Dn; k0 += 64) {
        #pragma unroll
        for (int q = 0; q < 4; ++q) {
            gload16(gA[q], As + ldsOff[q]);
            gload16(gB[q], Bs + ldsOff[q]);
            gA[q] += 64; gB[q] += 64;
        }
        __syncthreads();

        const int sh = lane >> 4;
        #pragma unroll
        for (int s = 0; s < 2; ++s) {
            bf16x8 af[4], bf[4];
            #pragma unroll
            for (int i = 0; i < 4; ++i) {
                int row = wm + i * 16 + (lane & 15);
                af[i] = *(const bf16x8*)(As + row * 128 + (((s * 4 + sh) ^ (row & 7)) << 4));
            }
            #pragma unroll
            for (int j = 0; j < 4; ++j) {
                int row = wn + j * 16 + (lane & 15);
                bf[j] = *(const bf16x8*)(Bs + row * 128 + (((s * 4 + sh) ^ (row & 7)) << 4));
            }
            #pragma unroll
            for (int i = 0; i < 4; ++i)
                #pragma unroll
                for (int j = 0; j < 4; ++j)
                    acc[i][j] = MFMA16(af[i], bf[j], acc[i][j]);
        }
        __syncthreads();
    }

    float bv4[4];
    #pragma unroll
    for (int j = 0; j < 4; ++j) bv4[j] = bv[n0 + wn + j * 16 + (lane & 15)];
    u16* Vhc_b = Vhc + (size_t)b * Ln * Dn;
    #pragma unroll
    for (int i = 0; i < 4; ++i) {
        #pragma unroll
        for (int r = 0; r < 4; ++r) {
            int m = m0 + wm + i * 16 + (lane >> 4) * 4 + r;
            u16* oh = Vhc_b + (size_t)m * Dn + n0 + wn;
            #pragma unroll
            for (int j = 0; j < 4; ++j)
                oh[j * 16 + (lane & 15)] = f2bf(acc[i][j][r] + bv4[j]);
        }
    }
}

// ---------------------------------------------------------------------------
// vtransc: Vtc[b][d][j] = Vhc[b][j][d]  (straight transpose, compacted rows)
// ---------------------------------------------------------------------------
__global__ __launch_bounds__(256) void vtransc_kernel(
    const u16* __restrict__ Vhc, const int* __restrict__ cnts,
    u16* __restrict__ Vtc)
{
    __shared__ u16 tile[64][72];
    const int b = blockIdx.z;
    const int l0 = blockIdx.y * 64, d0 = blockIdx.x * 64;
    if (l0 >= rup(cnts[b * 2], 64)) return;
    const int t = threadIdx.x;
    const int r = t >> 2, cq = (t & 3) * 16;

    const u16* src = Vhc + (size_t)(b * Ln + l0 + r) * Dn + d0 + cq;
    *(uint4*)&tile[r][cq]     = *(const uint4*)(src);
    *(uint4*)&tile[r][cq + 8] = *(const uint4*)(src + 8);
    __syncthreads();

    u16 tmp[16];
    #pragma unroll
    for (int i = 0; i < 16; ++i) tmp[i] = tile[cq + i][r];
    u16* dst = Vtc + (size_t)b * Dn * Ln + (size_t)(d0 + r) * Ln + l0 + cq;
    *(uint4*)(dst)     = *(uint4*)&tmp[0];
    *(uint4*)(dst + 8) = *(uint4*)&tmp[8];
}

// ---------------------------------------------------------------------------
// scorec: Ec[b,q,j] = bf16( Tb[b,q,:].Xk[b,kidx[j],:] + u[b,q] + vc[b,j] )
// for compacted j < kc; pad cols get bf16(MASKED). XCD-chunked 1D grid (2048).
// ---------------------------------------------------------------------------
__global__ __launch_bounds__(256) void scorec_kernel(
    const u16* __restrict__ Tb, const u16* __restrict__ Xk,
    const int* __restrict__ kidx, const int* __restrict__ cnts,
    const float* __restrict__ u, const float* __restrict__ vc,
    u16* __restrict__ Ec)
{
    __shared__ __align__(16) unsigned char As[128 * 128];
    __shared__ __align__(16) unsigned char Bs[128 * 128];

    // swizzle: nwg = 2048 = 8 * 256
    const int d = blockIdx.x;
    const int f = (d & 7) * 256 + (d >> 3);
    const int b = f >> 8;
    const int rem = f & 255;
    const int m0 = (rem >> 4) * 128;  // 16 q-tiles
    const int n0 = (rem & 15) * 128;  // 16 k-tiles

    const int kc_b = cnts[b * 2];
    if (n0 >= kc_b) return;
    const int tid = threadIdx.x, lane = tid & 63, wid = tid >> 6;
    const int wm = (wid >> 1) * 64, wn = (wid & 1) * 64;

    const size_t boff = (size_t)b * Ln * Dn;
    const u16* Tb_b = Tb + boff;
    const u16* Xk_b = Xk + boff;
    const int* kidx_b = kidx + b * Ln;

    const u16* gA[4]; const u16* gB[4]; int ldsOff[4];
    #pragma unroll
    for (int q = 0; q < 4; ++q) {
        int c = wid * 4 + q;
        int row = c * 8 + (lane >> 3);
        int sig = (lane & 7) ^ (row & 7);
        int grow = kidx_b[n0 + row];
        gA[q] = Tb_b + (size_t)(m0 + row) * Dn + sig * 8;
        gB[q] = Xk_b + (size_t)grow * Dn + sig * 8;
        ldsOff[q] = c * 1024;
    }

    f32x4 acc[4][4];
    const f32x4 z4 = {0.f, 0.f, 0.f, 0.f};
    #pragma unroll
    for (int i = 0; i < 4; ++i)
        #pragma unroll
        for (int j = 0; j < 4; ++j) acc[i][j] = z4;

    for (int k0 = 0; k0 < Dn; k0 += 64) {
        #pragma unroll
        for (int q = 0; q < 4; ++q) {
            gload16(gA[q], As + ldsOff[q]);
            gload16(gB[q], Bs + ldsOff[q]);
            gA[q] += 64; gB[q] += 64;
        }
        __syncthreads();

        const int sh = lane >> 4;
        #pragma unroll
        for (int s = 0; s < 2; ++s) {
            bf16x8 af[4], bf[4];
            #pragma unroll
            for (int i = 0; i < 4; ++i) {
                int row = wm + i * 16 + (lane & 15);
                af[i] = *(const bf16x8*)(As + row * 128 + (((s * 4 + sh) ^ (row & 7)) << 4));
            }
            #pragma unroll
            for (int j = 0; j < 4; ++j) {
                int row = wn + j * 16 + (lane & 15);
                bf[j] = *(const bf16x8*)(Bs + row * 128 + (((s * 4 + sh) ^ (row & 7)) << 4));
            }
            #pragma unroll
            for (int i = 0; i < 4; ++i)
                #pragma unroll
                for (int j = 0; j < 4; ++j)
                    acc[i][j] = MFMA16(af[i], bf[j], acc[i][j]);
        }
        __syncthreads();
    }

    float vcl[4];
    #pragma unroll
    for (int j = 0; j < 4; ++j) vcl[j] = vc[b * Ln + n0 + wn + j * 16 + (lane & 15)];
    #pragma unroll
    for (int i = 0; i < 4; ++i) {
        #pragma unroll
        for (int r = 0; r < 4; ++r) {
            int m = m0 + wm + i * 16 + (lane >> 4) * 4 + r;
            float um = u[b * Ln + m];
            u16* orow = Ec + ((size_t)(b * Ln + m)) * Ln + n0 + wn;
            #pragma unroll
            for (int j = 0; j < 4; ++j) {
                int jj = n0 + wn + j * 16 + (lane & 15);
                orow[j * 16 + (lane & 15)] =
                    f2bf((jj < kc_b) ? (acc[i][j][r] + um + vcl[j]) : MASKED_VAL);
            }
        }
    }
}

// ---------------------------------------------------------------------------
// stats_expand: one block per (b,q) row. Pass 1: block-reduce max and
// 1/sum(exp) over compacted cols (same math as before -> bit-identical
// stats). Pass 2: expand bf16 Ec row -> full masked f32 e row (kpos gather,
// row is L1-resident from pass 1).
// ---------------------------------------------------------------------------
__global__ __launch_bounds__(256) void stats_expand_kernel(
    const u16* __restrict__ Ec, const int* __restrict__ kpos,
    const int* __restrict__ cnts, float* __restrict__ stats,
    float* __restrict__ e)
{
    __shared__ float redm[4];
    __shared__ float reds[4];
    const int row = blockIdx.x;
    const int b = row >> 11;
    const int bound = rup(cnts[b * 2], 64);
    const int t = threadIdx.x;
    const int lane = t & 63, wave = t >> 6;
    const u16* er = Ec + (size_t)row * Ln;

    float v[8];
    {
        int base = t * 8;
        if (base < bound) {
            uint4 x = *(const uint4*)(er + base);
            const u16* xs = (const u16*)&x;
            #pragma unroll
            for (int j = 0; j < 8; ++j) v[j] = bf2f(xs[j]);
        } else {
            #pragma unroll
            for (int j = 0; j < 8; ++j) v[j] = MASKED_VAL;
        }
    }

    float mx = v[0];
    #pragma unroll
    for (int j = 1; j < 8; ++j) mx = fmaxf(mx, v[j]);
    #pragma unroll
    for (int o = 32; o > 0; o >>= 1) mx = fmaxf(mx, __shfl_xor(mx, o, 64));
    if (lane == 0) redm[wave] = mx;
    __syncthreads();
    mx = fmaxf(fmaxf(redm[0], redm[1]), fmaxf(redm[2], redm[3]));

    float s = 0.f;
    #pragma unroll
    for (int j = 0; j < 8; ++j) s += __expf(v[j] - mx);
    #pragma unroll
    for (int o = 32; o > 0; o >>= 1) s += __shfl_xor(s, o, 64);
    if (lane == 0) reds[wave] = s;
    __syncthreads();
    s = reds[0] + reds[1] + reds[2] + reds[3];

    if (t == 0) {
        stats[row * 2]     = mx;
        stats[row * 2 + 1] = 1.0f / s;
    }

    // expansion (no barrier needed: reads Ec, writes e)
    const int* kp = kpos + b * Ln;
    const int k = t * 8;
    int p[8];
    *(int4*)&p[0] = *(const int4*)(kp + k);
    *(int4*)&p[4] = *(const int4*)(kp + k + 4);
    float o[8];
    #pragma unroll
    for (int j = 0; j < 8; ++j)
        o[j] = (p[j] >= 0) ? bf2f(er[p[j]]) : MASKED_VAL;

    float* eo = e + (size_t)row * Ln + k;
    *(float4*)(eo)     = make_float4(o[0], o[1], o[2], o[3]);
    *(float4*)(eo + 4) = make_float4(o[4], o[5], o[6], o[7]);
}

// ---------------------------------------------------------------------------
// pvc: a[qidx[i], :] = P(compact) @ Vtc^T over compacted k; rows q-compacted.
// P built from bf16 Ec. XCD-chunked 1D grid (1024).
// ---------------------------------------------------------------------------
__global__ __launch_bounds__(256) void pvc_kernel(
    const u16* __restrict__ Ec, const u16* __restrict__ Vtc,
    const float* __restrict__ stats, const int* __restrict__ qidx,
    const int* __restrict__ cnts, float* __restrict__ out_a)
{
    __shared__ __align__(16) unsigned char As[128 * 128];
    __shared__ __align__(16) unsigned char Bs[128 * 128];

    // swizzle: nwg = 1024 = 8 * 128
    const int d = blockIdx.x;
    const int f = (d & 7) * 128 + (d >> 3);
    const int b = f >> 7;
    const int rem = f & 127;
    const int m0 = (rem >> 3) * 128;  // 16 compacted q tiles
    const int n0 = (rem & 7) * 128;   // 8 d tiles

    const int kc_b = cnts[b * 2], qc_b = cnts[b * 2 + 1];
    if (m0 >= rup(qc_b, 128)) return;
    const int kbound = rup(kc_b, 64);
    const int tid = threadIdx.x, lane = tid & 63, wid = tid >> 6;
    const int wm = (wid >> 1) * 64, wn = (wid & 1) * 64;

    const u16* Ec_b  = Ec  + (size_t)b * Ln * Ln;
    const u16* Vtc_b = Vtc + (size_t)b * Dn * Ln;
    const int* qidx_b = qidx + b * Ln;

    const int srow = tid >> 1, half = tid & 1;
    const int grow = qidx_b[m0 + srow];
    const u16* srcP = Ec_b + (size_t)grow * Ln + half * 32;
    const float smx  = stats[(b * Ln + grow) * 2];
    const float sinv = stats[(b * Ln + grow) * 2 + 1];
    unsigned char* wA = As + srow * 128;
    int sl[4];
    #pragma unroll
    for (int c = 0; c < 4; ++c) sl[c] = (((half * 4 + c) ^ (srow & 7)) << 4);

    const u16* gB[4];
    #pragma unroll
    for (int q = 0; q < 4; ++q) {
        int c = wid * 4 + q;
        int row = c * 8 + (lane >> 3);
        int sig = (lane & 7) ^ (row & 7);
        gB[q] = Vtc_b + (size_t)(n0 + row) * Ln + sig * 8;
    }

    f32x4 acc[4][4];
    const f32x4 z4 = {0.f, 0.f, 0.f, 0.f};
    #pragma unroll
    for (int i = 0; i < 4; ++i)
        #pragma unroll
        for (int j = 0; j < 4; ++j) acc[i][j] = z4;

    for (int k0 = 0; k0 < kbound; k0 += 64) {
        #pragma unroll
        for (int q = 0; q < 4; ++q) {
            gload16(gB[q], Bs + (wid * 4 + q) * 1024);
            gB[q] += 64;
        }
        u16 tmp[32];
        *(uint4*)&tmp[0]  = *(const uint4*)(srcP);
        *(uint4*)&tmp[8]  = *(const uint4*)(srcP + 8);
        *(uint4*)&tmp[16] = *(const uint4*)(srcP + 16);
        *(uint4*)&tmp[24] = *(const uint4*)(srcP + 24);
        srcP += 64;
        float fe[32];
        #pragma unroll
        for (int j = 0; j < 32; ++j) fe[j] = bf2f(tmp[j]);
        #pragma unroll
        for (int c = 0; c < 4; ++c) {
            u32 p0 = pack2(__expf(fe[c*8+0] - smx) * sinv, __expf(fe[c*8+1] - smx) * sinv);
            u32 p1 = pack2(__expf(fe[c*8+2] - smx) * sinv, __expf(fe[c*8+3] - smx) * sinv);
            u32 p2 = pack2(__expf(fe[c*8+4] - smx) * sinv, __expf(fe[c*8+5] - smx) * sinv);
            u32 p3 = pack2(__expf(fe[c*8+6] - smx) * sinv, __expf(fe[c*8+7] - smx) * sinv);
            *(uint4*)(wA + sl[c]) = make_uint4(p0, p1, p2, p3);
        }
        __syncthreads();

        const int sh = lane >> 4;
        #pragma unroll
        for (int s = 0; s < 2; ++s) {
            bf16x8 af[4], bv[4];
            #pragma unroll
            for (int i = 0; i < 4; ++i) {
                int row = wm + i * 16 + (lane & 15);
                af[i] = *(const bf16x8*)(As + row * 128 + (((s * 4 + sh) ^ (row & 7)) << 4));
            }
            #pragma unroll
            for (int j = 0; j < 4; ++j) {
                int row = wn + j * 16 + (lane & 15);
                bv[j] = *(const bf16x8*)(Bs + row * 128 + (((s * 4 + sh) ^ (row & 7)) << 4));
            }
            #pragma unroll
            for (int i = 0; i < 4; ++i)
                #pragma unroll
                for (int j = 0; j < 4; ++j)
                    acc[i][j] = MFMA16(af[i], bv[j], acc[i][j]);
        }
        __syncthreads();
    }

    #pragma unroll
    for (int i = 0; i < 4; ++i) {
        #pragma unroll
        for (int r = 0; r < 4; ++r) {
            int gi = m0 + wm + i * 16 + (lane >> 4) * 4 + r;
            if (gi < qc_b) {
                int gm = qidx_b[gi];
                float* orow = out_a + (size_t)(b * Ln + gm) * Dn + n0 + wn;
                #pragma unroll
                for (int j = 0; j < 4; ++j)
                    orow[j * 16 + (lane & 15)] = acc[i][j][r];
            }
        }
    }
}

// ---------------------------------------------------------------------------
extern "C" void kernel_launch(void* const* d_in, const int* in_sizes, int n_in,
                              void* d_out, int out_size, void* d_ws, size_t ws_size,
                              hipStream_t stream)
{
    const float* Q  = (const float*)d_in[0];
    const float* K  = (const float*)d_in[1];
    const float* V  = (const float*)d_in[2];
    const float* Wq = (const float*)d_in[3];
    const float* bq = (const float*)d_in[4];
    const float* Wk = (const float*)d_in[5];
    const float* bk = (const float*)d_in[6];
    const float* Wv = (const float*)d_in[7];
    const float* bv = (const float*)d_in[8];
    const int* q_mask = (const int*)d_in[9];
    const int* k_mask = (const int*)d_in[10];

    float* out_a = (float*)d_out;                       // [B, L, D]
    float* out_e = out_a + (size_t)Bn * Ln * Dn;        // [B, L, L]

    const size_t NE = (size_t)Bn * Ln * Dn;             // 16,777,216
    const size_t NW = (size_t)Dn * Dn;                  // 1,048,576
    const int BL = Bn * Ln;                             // 16,384

    // ws layout: Tb Vhc Vtc [Vbf Xq -> Ec alias] Xk Wvb Wqt Wkt Mt + tables
    u16* Tb  = (u16*)d_ws;
    u16* Vhc = Tb + NE;
    u16* Vtc = Vhc + NE;
    u16* Vbf = Vtc + NE;
    u16* Xq  = Vbf + NE;
    u16* Xk  = Xq + NE;
    u16* Wvb = Xk + NE;
    u16* Wqt = Wvb + NW;
    u16* Wkt = Wqt + NW;
    u16* Mt  = Wkt + NW;
    float* w1    = (float*)(Mt + NW);
    float* w2    = w1 + Dn;
    float* cbuf  = w2 + Dn;
    float* uarr  = cbuf + 4;
    float* varr  = uarr + BL;
    float* vc    = varr + BL;
    float* stats = vc + BL;
    int* kidx = (int*)(stats + 2 * BL);
    int* kpos = kidx + BL;
    int* qidx = kpos + BL;
    int* cnts = qidx + BL;

    // Ec (bf16 e', 2*NE u16) aliases Vbf+Xq, both dead after projv/rowdot.
    u16* Ec = Vbf;

    dim3 blk(256);

    // 0) mask compaction tables
    prep_kernel<<<dim3(Bn), blk, 0, stream>>>(k_mask, q_mask, kidx, kpos, qidx, cnts);

    // 1) input conversions (bf16)
    convert3_kernel<<<dim3(3 * (NE / 2048)), blk, 0, stream>>>(
        Q, K, V, Xq, Xk, Vbf, (int)(NE / 2048));
    convert_single_kernel<<<dim3(NW / 2048), blk, 0, stream>>>(Wv, Wvb, (int)NW);

    // 2) weight transposes + bias-fold vectors + c
    wtrans_kernel<<<dim3(16, 16, 2), blk, 0, stream>>>(Wq, Wk, Wqt, Wkt);
    ck_kernel<<<dim3(1), dim3(64), 0, stream>>>(bq, bk, cbuf);
    wvec_kernel<<<dim3(256, 2), blk, 0, stream>>>(Wqt, Wkt, bk, bq, w1, w2);

    // 3) Mt = Wk^T Wq (transposed result), bf16
    mgemm_kernel<<<dim3(8, 8), blk, 0, stream>>>(Wkt, Wqt, Mt);

    // 4) T = Xq @ M ; Vhc = gather(V)@Wv^T + bv (k-compacted rows only)
    proj2_kernel<<<dim3(Dn / 128, BL / 128), blk, 0, stream>>>(Xq, Mt, Tb);
    projv_kernel<<<dim3(Dn / 128, Ln / 128, Bn), blk, 0, stream>>>(
        Vbf, Wvb, bv, kidx, cnts, Vhc);

    // 5) u = Xq.w1 + c, v = Xk.w2; gather vc = v[kidx]  (Xq dead after this)
    rowdot_kernel<<<dim3(BL / 4, 2), blk, 0, stream>>>(Xq, Xk, w1, w2, cbuf, uarr, varr);
    vcg_kernel<<<dim3(Bn), blk, 0, stream>>>(varr, kidx, vc);

    // 6) straight transpose of compacted V
    vtransc_kernel<<<dim3(Dn / 64, Ln / 64, Bn), blk, 0, stream>>>(Vhc, cnts, Vtc);

    // 7) compacted scores -> bf16 Ec (overwrites dead Vbf/Xq)
    scorec_kernel<<<dim3(2048), blk, 0, stream>>>(Tb, Xk, kidx, cnts, uarr, vc, Ec);

    // 8) fused softmax stats + expand to f32 e
    stats_expand_kernel<<<dim3(BL), blk, 0, stream>>>(Ec, kpos, cnts, stats, out_e);

    // 9) zero masked-q rows of a, then compacted PV (bf16 P source)
    zeroa_kernel<<<dim3(BL), blk, 0, stream>>>((float4*)out_a, q_mask);
    pvc_kernel<<<dim3(1024), blk, 0, stream>>>(Ec, Vtc, stats, qidx, cnts, out_a);
}

// Round 10
// 356.726 us; speedup vs baseline: 1.3837x; 1.1039x over previous
//
#include <hip/hip_runtime.h>
#include <cstddef>
#include <cstdint>

constexpr int Bn = 8;
constexpr int Ln = 2048;
constexpr int Dn = 1024;
constexpr float MASKED_VAL = -2147483648.0f;  // -2^31

typedef unsigned short u16;
typedef unsigned int   u32;
typedef __attribute__((ext_vector_type(8))) __bf16 bf16x8;
typedef __attribute__((ext_vector_type(4))) float  f32x4;

__device__ __forceinline__ u16 f2bf(float x) {
    u32 u = __float_as_uint(x);
    u += 0x7FFFu + ((u >> 16) & 1u);
    return (u16)(u >> 16);
}
__device__ __forceinline__ float bf2f(u16 h) {
    return __uint_as_float(((u32)h) << 16);
}
__device__ __forceinline__ u32 pack2(float a, float b) {
    return (u32)f2bf(a) | ((u32)f2bf(b) << 16);
}
__device__ __forceinline__ int rup(int x, int m) { return (x + m - 1) & ~(m - 1); }

__device__ __forceinline__ void gload16(const void* g, void* l) {
    typedef const __attribute__((address_space(1))) unsigned int* gp_t;
    typedef __attribute__((address_space(3))) unsigned int* lp_t;
    __builtin_amdgcn_global_load_lds((gp_t)g, (lp_t)l, 16, 0, 0);
}

#define MFMA16(a, b, c) __builtin_amdgcn_mfma_f32_16x16x32_bf16((a), (b), (c), 0, 0, 0)

// ---------------------------------------------------------------------------
// prep: per batch, compaction tables. kidx (padded w/ last valid), kpos
// (-1 if masked), qidx (padded w/ 0), qpos (-1 if masked), counts.
// ---------------------------------------------------------------------------
__global__ __launch_bounds__(256) void prep_kernel(
    const int* __restrict__ k_mask, const int* __restrict__ q_mask,
    int* __restrict__ kidx, int* __restrict__ kpos,
    int* __restrict__ qidx, int* __restrict__ qpos, int* __restrict__ cnts)
{
    __shared__ int sc[256];
    __shared__ int lastv;
    const int b = blockIdx.x, t = threadIdx.x;
    for (int pass = 0; pass < 2; ++pass) {
        const int* msk = (pass ? q_mask : k_mask) + b * Ln;
        int* idx = (pass ? qidx : kidx) + b * Ln;
        int* pos = (pass ? qpos : kpos) + b * Ln;
        int f[8], s = 0;
        #pragma unroll
        for (int j = 0; j < 8; ++j) { f[j] = (msk[t * 8 + j] != 0) ? 1 : 0; s += f[j]; }
        sc[t] = s;
        __syncthreads();
        #pragma unroll
        for (int o = 1; o < 256; o <<= 1) {
            int v = (t >= o) ? sc[t - o] : 0;
            __syncthreads();
            sc[t] += v;
            __syncthreads();
        }
        int incl = sc[t];
        int total = sc[255];
        int p = incl - s;
        #pragma unroll
        for (int j = 0; j < 8; ++j) {
            pos[t * 8 + j] = f[j] ? p : -1;
            if (f[j]) { idx[p] = t * 8 + j; ++p; }
        }
        __syncthreads();
        if (t == 0) {
            cnts[b * 2 + pass] = total;
            lastv = (total > 0) ? idx[total - 1] : 0;
        }
        __syncthreads();
        int padv = (pass == 0) ? lastv : 0;
        for (int e2 = total + t; e2 < Ln; e2 += 256) idx[e2] = padv;
        __syncthreads();
    }
}

// ---------------------------------------------------------------------------
// convert_single: fp32 -> bf16 (full array).
// ---------------------------------------------------------------------------
__global__ __launch_bounds__(256) void convert_single_kernel(
    const float* __restrict__ src, u16* __restrict__ dh, int n)
{
    int i = (blockIdx.x * 256 + threadIdx.x) * 8;
    if (i >= n) return;
    float f[8];
    *(float4*)&f[0] = *(const float4*)(src + i);
    *(float4*)&f[4] = *(const float4*)(src + i + 4);
    u32 H[4];
    #pragma unroll
    for (int j = 0; j < 4; ++j) H[j] = pack2(f[2*j], f[2*j+1]);
    *(uint4*)(dh + i) = make_uint4(H[0], H[1], H[2], H[3]);
}

// ---------------------------------------------------------------------------
// convgather: Xkc[b][j][:] = bf16(K[b][kidx[b][j]][:]) (y=0) and same for
// V->Vc (y=1); only compacted rows j < rup(kc,128). One block per row.
// ---------------------------------------------------------------------------
__global__ __launch_bounds__(256) void convgather_kernel(
    const float* __restrict__ K, const float* __restrict__ V,
    const int* __restrict__ kidx, const int* __restrict__ cnts,
    u16* __restrict__ Xkc, u16* __restrict__ Vc)
{
    const int b = blockIdx.z, j = blockIdx.x, y = blockIdx.y;
    if (j >= rup(cnts[b * 2], 128)) return;
    const int src_row = kidx[b * Ln + j];
    const float* src = (y ? V : K) + ((size_t)b * Ln + src_row) * Dn;
    u16* dst = (y ? Vc : Xkc) + ((size_t)b * Ln + j) * Dn;
    const int t = threadIdx.x;
    float4 f = *(const float4*)(src + t * 4);
    *(uint2*)(dst + t * 4) = make_uint2(pack2(f.x, f.y), pack2(f.z, f.w));
}

// ---------------------------------------------------------------------------
// wtrans: W (fp32 [e][d]) -> Wt (bf16 [d][e]) for Wq and Wk (z selects).
// ---------------------------------------------------------------------------
__global__ __launch_bounds__(256) void wtrans_kernel(
    const float* __restrict__ Wq, const float* __restrict__ Wk,
    u16* __restrict__ Wqt, u16* __restrict__ Wkt)
{
    __shared__ float tile[64][68];
    const float* src = blockIdx.z ? Wk : Wq;
    u16* dst = blockIdx.z ? Wkt : Wqt;
    const int e0 = blockIdx.y * 64, d0 = blockIdx.x * 64;
    const int t = threadIdx.x;
    const int r = t >> 2, cq = (t & 3) * 16;
    const float* s = src + (size_t)(e0 + r) * Dn + d0 + cq;
    #pragma unroll
    for (int i = 0; i < 4; ++i)
        *(float4*)&tile[r][cq + i * 4] = *(const float4*)(s + i * 4);
    __syncthreads();
    u32 o[8];
    #pragma unroll
    for (int i = 0; i < 8; ++i)
        o[i] = pack2(tile[cq + 2 * i][r], tile[cq + 2 * i + 1][r]);
    u16* d = dst + (size_t)(d0 + r) * Dn + e0 + cq;
    *(uint4*)(d)     = make_uint4(o[0], o[1], o[2], o[3]);
    *(uint4*)(d + 8) = make_uint4(o[4], o[5], o[6], o[7]);
}

// ---------------------------------------------------------------------------
// ck: cbuf[0] = bq . bk
// ---------------------------------------------------------------------------
__global__ __launch_bounds__(64) void ck_kernel(
    const float* __restrict__ bq, const float* __restrict__ bk, float* __restrict__ cbuf)
{
    int l = threadIdx.x;
    float s = 0.f;
    #pragma unroll
    for (int i = 0; i < 16; ++i) s += bq[l + 64 * i] * bk[l + 64 * i];
    #pragma unroll
    for (int o = 32; o; o >>= 1) s += __shfl_xor(s, o, 64);
    if (l == 0) cbuf[0] = s;
}

// ---------------------------------------------------------------------------
// wvec: w1[d] = Wqt[d,:].bk ; w2[d] = Wkt[d,:].bq   (one wave per d)
// ---------------------------------------------------------------------------
__global__ __launch_bounds__(256) void wvec_kernel(
    const u16* __restrict__ Wqt, const u16* __restrict__ Wkt,
    const float* __restrict__ bk, const float* __restrict__ bq,
    float* __restrict__ w1, float* __restrict__ w2)
{
    const int y = blockIdx.y;
    const u16* src = y ? Wkt : Wqt;
    const float* vec = y ? bq : bk;
    float* out = y ? w2 : w1;
    const int d = blockIdx.x * 4 + (threadIdx.x >> 6);
    const int l = threadIdx.x & 63;
    float s = 0.f;
    #pragma unroll
    for (int i = 0; i < 16; ++i) {
        int e = l + 64 * i;
        s += bf2f(src[(size_t)d * Dn + e]) * vec[e];
    }
    #pragma unroll
    for (int o = 32; o; o >>= 1) s += __shfl_xor(s, o, 64);
    if (l == 0) out[d] = s;
}

// ---------------------------------------------------------------------------
// rowdot: y=0: u[row] = Xq[row,:].w1 + c (all rows);
//         y=1: vc[row] = Xkc[row,:].w2 (compacted rows; pad rows harmless).
// ---------------------------------------------------------------------------
__global__ __launch_bounds__(256) void rowdot_kernel(
    const u16* __restrict__ Xq, const u16* __restrict__ Xkc,
    const float* __restrict__ w1, const float* __restrict__ w2,
    const float* __restrict__ cbuf, float* __restrict__ u, float* __restrict__ vc)
{
    const int y = blockIdx.y;
    const u16* x = y ? Xkc : Xq;
    const float* w = y ? w2 : w1;
    float* out = y ? vc : u;
    const int row = blockIdx.x * 4 + (threadIdx.x >> 6);
    const int l = threadIdx.x & 63;
    float s = 0.f;
    #pragma unroll
    for (int h = 0; h < 2; ++h) {
        const u16* xp = x + (size_t)row * Dn + h * 512 + l * 8;
        const float* wp = w + h * 512 + l * 8;
        uint4 xv = *(const uint4*)xp;
        float4 wa = *(const float4*)(wp);
        float4 wb = *(const float4*)(wp + 4);
        const u16* xs = (const u16*)&xv;
        s += bf2f(xs[0]) * wa.x + bf2f(xs[1]) * wa.y + bf2f(xs[2]) * wa.z + bf2f(xs[3]) * wa.w
           + bf2f(xs[4]) * wb.x + bf2f(xs[5]) * wb.y + bf2f(xs[6]) * wb.z + bf2f(xs[7]) * wb.w;
    }
    #pragma unroll
    for (int o = 32; o; o >>= 1) s += __shfl_xor(s, o, 64);
    if (l == 0) out[row] = s + (y ? 0.0f : cbuf[0]);
}

// ---------------------------------------------------------------------------
// zeroa: zero a-rows where q_mask==0 (pvc writes all other rows fully).
// ---------------------------------------------------------------------------
__global__ __launch_bounds__(256) void zeroa_kernel(
    float4* __restrict__ out_a, const int* __restrict__ q_mask)
{
    const int row = blockIdx.x;
    if (q_mask[row]) return;
    out_a[(size_t)row * 256 + threadIdx.x] = make_float4(0.f, 0.f, 0.f, 0.f);
}

// ---------------------------------------------------------------------------
// mgemm: Mt[d'][d] = sum_e Wkt[d',e] * Wqt[d,e]   (1024x1024x1024, bf16 out)
// ---------------------------------------------------------------------------
__global__ __launch_bounds__(256) void mgemm_kernel(
    const u16* __restrict__ Wkt, const u16* __restrict__ Wqt, u16* __restrict__ Mt)
{
    __shared__ __align__(16) unsigned char As[128 * 128];
    __shared__ __align__(16) unsigned char Bs[128 * 128];

    const int m0 = blockIdx.y * 128, n0 = blockIdx.x * 128;
    const int tid = threadIdx.x, lane = tid & 63, wid = tid >> 6;
    const int wm = (wid >> 1) * 64, wn = (wid & 1) * 64;

    const u16* gA[4]; const u16* gB[4]; int ldsOff[4];
    #pragma unroll
    for (int q = 0; q < 4; ++q) {
        int c = wid * 4 + q;
        int row = c * 8 + (lane >> 3);
        int sig = (lane & 7) ^ (row & 7);
        gA[q] = Wkt + (size_t)(m0 + row) * Dn + sig * 8;
        gB[q] = Wqt + (size_t)(n0 + row) * Dn + sig * 8;
        ldsOff[q] = c * 1024;
    }

    f32x4 acc[4][4];
    const f32x4 z4 = {0.f, 0.f, 0.f, 0.f};
    #pragma unroll
    for (int i = 0; i < 4; ++i)
        #pragma unroll
        for (int j = 0; j < 4; ++j) acc[i][j] = z4;

    for (int k0 = 0; k0 < Dn; k0 += 64) {
        #pragma unroll
        for (int q = 0; q < 4; ++q) {
            gload16(gA[q], As + ldsOff[q]);
            gload16(gB[q], Bs + ldsOff[q]);
            gA[q] += 64; gB[q] += 64;
        }
        __syncthreads();

        const int sh = lane >> 4;
        #pragma unroll
        for (int s = 0; s < 2; ++s) {
            bf16x8 af[4], bf[4];
            #pragma unroll
            for (int i = 0; i < 4; ++i) {
                int row = wm + i * 16 + (lane & 15);
                af[i] = *(const bf16x8*)(As + row * 128 + (((s * 4 + sh) ^ (row & 7)) << 4));
            }
            #pragma unroll
            for (int j = 0; j < 4; ++j) {
                int row = wn + j * 16 + (lane & 15);
                bf[j] = *(const bf16x8*)(Bs + row * 128 + (((s * 4 + sh) ^ (row & 7)) << 4));
            }
            #pragma unroll
            for (int i = 0; i < 4; ++i)
                #pragma unroll
                for (int j = 0; j < 4; ++j)
                    acc[i][j] = MFMA16(af[i], bf[j], acc[i][j]);
        }
        __syncthreads();
    }

    #pragma unroll
    for (int i = 0; i < 4; ++i) {
        #pragma unroll
        for (int r = 0; r < 4; ++r) {
            int m = m0 + wm + i * 16 + (lane >> 4) * 4 + r;
            u16* oh = Mt + (size_t)m * Dn + n0 + wn;
            #pragma unroll
            for (int j = 0; j < 4; ++j)
                oh[j * 16 + (lane & 15)] = f2bf(acc[i][j][r]);
        }
    }
}

// ---------------------------------------------------------------------------
// proj2: Tb = Xq @ Mt^T (no bias). Grid (Dn/128, BL/128).
// ---------------------------------------------------------------------------
__global__ __launch_bounds__(256) void proj2_kernel(
    const u16* __restrict__ Xq, const u16* __restrict__ Mt, u16* __restrict__ Tb)
{
    __shared__ __align__(16) unsigned char As[128 * 128];
    __shared__ __align__(16) unsigned char Bs[128 * 128];

    const int m0 = blockIdx.y * 128, n0 = blockIdx.x * 128;
    const int tid = threadIdx.x, lane = tid & 63, wid = tid >> 6;
    const int wm = (wid >> 1) * 64, wn = (wid & 1) * 64;

    const u16* gA[4]; const u16* gB[4]; int ldsOff[4];
    #pragma unroll
    for (int q = 0; q < 4; ++q) {
        int c = wid * 4 + q;
        int row = c * 8 + (lane >> 3);
        int sig = (lane & 7) ^ (row & 7);
        gA[q] = Xq + (size_t)(m0 + row) * Dn + sig * 8;
        gB[q] = Mt + (size_t)(n0 + row) * Dn + sig * 8;
        ldsOff[q] = c * 1024;
    }

    f32x4 acc[4][4];
    const f32x4 z4 = {0.f, 0.f, 0.f, 0.f};
    #pragma unroll
    for (int i = 0; i < 4; ++i)
        #pragma unroll
        for (int j = 0; j < 4; ++j) acc[i][j] = z4;

    for (int k0 = 0; k0 < Dn; k0 += 64) {
        #pragma unroll
        for (int q = 0; q < 4; ++q) {
            gload16(gA[q], As + ldsOff[q]);
            gload16(gB[q], Bs + ldsOff[q]);
            gA[q] += 64; gB[q] += 64;
        }
        __syncthreads();

        const int sh = lane >> 4;
        #pragma unroll
        for (int s = 0; s < 2; ++s) {
            bf16x8 af[4], bf[4];
            #pragma unroll
            for (int i = 0; i < 4; ++i) {
                int row = wm + i * 16 + (lane & 15);
                af[i] = *(const bf16x8*)(As + row * 128 + (((s * 4 + sh) ^ (row & 7)) << 4));
            }
            #pragma unroll
            for (int j = 0; j < 4; ++j) {
                int row = wn + j * 16 + (lane & 15);
                bf[j] = *(const bf16x8*)(Bs + row * 128 + (((s * 4 + sh) ^ (row & 7)) << 4));
            }
            #pragma unroll
            for (int i = 0; i < 4; ++i)
                #pragma unroll
                for (int j = 0; j < 4; ++j)
                    acc[i][j] = MFMA16(af[i], bf[j], acc[i][j]);
        }
        __syncthreads();
    }

    #pragma unroll
    for (int i = 0; i < 4; ++i) {
        #pragma unroll
        for (int r = 0; r < 4; ++r) {
            int m = m0 + wm + i * 16 + (lane >> 4) * 4 + r;
            u16* oh = Tb + (size_t)m * Dn + n0 + wn;
            #pragma unroll
            for (int j = 0; j < 4; ++j)
                oh[j * 16 + (lane & 15)] = f2bf(acc[i][j][r]);
        }
    }
}

// ---------------------------------------------------------------------------
// projv: Vhc[b][j][:] = Vc[b][j][:] @ Wvb^T + bv (compacted rows, linear A).
// ---------------------------------------------------------------------------
__global__ __launch_bounds__(256) void projv_kernel(
    const u16* __restrict__ Vc, const u16* __restrict__ Wvb,
    const float* __restrict__ bv, const int* __restrict__ cnts,
    u16* __restrict__ Vhc)
{
    __shared__ __align__(16) unsigned char As[128 * 128];
    __shared__ __align__(16) unsigned char Bs[128 * 128];

    const int b = blockIdx.z;
    const int kc_b = cnts[b * 2];
    const int m0 = blockIdx.y * 128;
    if (m0 >= rup(kc_b, 128)) return;
    const int n0 = blockIdx.x * 128;
    const int tid = threadIdx.x, lane = tid & 63, wid = tid >> 6;
    const int wm = (wid >> 1) * 64, wn = (wid & 1) * 64;

    const u16* Vc_b = Vc + (size_t)b * Ln * Dn;

    const u16* gA[4]; const u16* gB[4]; int ldsOff[4];
    #pragma unroll
    for (int q = 0; q < 4; ++q) {
        int c = wid * 4 + q;
        int row = c * 8 + (lane >> 3);
        int sig = (lane & 7) ^ (row & 7);
        gA[q] = Vc_b + (size_t)(m0 + row) * Dn + sig * 8;
        gB[q] = Wvb + (size_t)(n0 + row) * Dn + sig * 8;
        ldsOff[q] = c * 1024;
    }

    f32x4 acc[4][4];
    const f32x4 z4 = {0.f, 0.f, 0.f, 0.f};
    #pragma unroll
    for (int i = 0; i < 4; ++i)
        #pragma unroll
        for (int j = 0; j < 4; ++j) acc[i][j] = z4;

    for (int k0 = 0; k0 < Dn; k0 += 64) {
        #pragma unroll
        for (int q = 0; q < 4; ++q) {
            gload16(gA[q], As + ldsOff[q]);
            gload16(gB[q], Bs + ldsOff[q]);
            gA[q] += 64; gB[q] += 64;
        }
        __syncthreads();

        const int sh = lane >> 4;
        #pragma unroll
        for (int s = 0; s < 2; ++s) {
            bf16x8 af[4], bf[4];
            #pragma unroll
            for (int i = 0; i < 4; ++i) {
                int row = wm + i * 16 + (lane & 15);
                af[i] = *(const bf16x8*)(As + row * 128 + (((s * 4 + sh) ^ (row & 7)) << 4));
            }
            #pragma unroll
            for (int j = 0; j < 4; ++j) {
                int row = wn + j * 16 + (lane & 15);
                bf[j] = *(const bf16x8*)(Bs + row * 128 + (((s * 4 + sh) ^ (row & 7)) << 4));
            }
            #pragma unroll
            for (int i = 0; i < 4; ++i)
                #pragma unroll
                for (int j = 0; j < 4; ++j)
                    acc[i][j] = MFMA16(af[i], bf[j], acc[i][j]);
        }
        __syncthreads();
    }

    float bv4[4];
    #pragma unroll
    for (int j = 0; j < 4; ++j) bv4[j] = bv[n0 + wn + j * 16 + (lane & 15)];
    u16* Vhc_b = Vhc + (size_t)b * Ln * Dn;
    #pragma unroll
    for (int i = 0; i < 4; ++i) {
        #pragma unroll
        for (int r = 0; r < 4; ++r) {
            int m = m0 + wm + i * 16 + (lane >> 4) * 4 + r;
            u16* oh = Vhc_b + (size_t)m * Dn + n0 + wn;
            #pragma unroll
            for (int j = 0; j < 4; ++j)
                oh[j * 16 + (lane & 15)] = f2bf(acc[i][j][r] + bv4[j]);
        }
    }
}

// ---------------------------------------------------------------------------
// vtransc: Vtc[b][d][j] = Vhc[b][j][d]  (straight transpose, compacted rows)
// ---------------------------------------------------------------------------
__global__ __launch_bounds__(256) void vtransc_kernel(
    const u16* __restrict__ Vhc, const int* __restrict__ cnts,
    u16* __restrict__ Vtc)
{
    __shared__ u16 tile[64][72];
    const int b = blockIdx.z;
    const int l0 = blockIdx.y * 64, d0 = blockIdx.x * 64;
    if (l0 >= rup(cnts[b * 2], 64)) return;
    const int t = threadIdx.x;
    const int r = t >> 2, cq = (t & 3) * 16;

    const u16* src = Vhc + (size_t)(b * Ln + l0 + r) * Dn + d0 + cq;
    *(uint4*)&tile[r][cq]     = *(const uint4*)(src);
    *(uint4*)&tile[r][cq + 8] = *(const uint4*)(src + 8);
    __syncthreads();

    u16 tmp[16];
    #pragma unroll
    for (int i = 0; i < 16; ++i) tmp[i] = tile[cq + i][r];
    u16* dst = Vtc + (size_t)b * Dn * Ln + (size_t)(d0 + r) * Ln + l0 + cq;
    *(uint4*)(dst)     = *(uint4*)&tmp[0];
    *(uint4*)(dst + 8) = *(uint4*)&tmp[8];
}

// ---------------------------------------------------------------------------
// scorec: Ec[b,q,j] = bf16( Tb[b,q,:].Xkc[b,j,:] + u[b,q] + vc[b,j] )
// for compacted j < kc; pad cols get bf16(MASKED). All-linear staging.
// XCD-chunked 1D grid (2048).
// ---------------------------------------------------------------------------
__global__ __launch_bounds__(256) void scorec_kernel(
    const u16* __restrict__ Tb, const u16* __restrict__ Xkc,
    const int* __restrict__ cnts,
    const float* __restrict__ u, const float* __restrict__ vc,
    u16* __restrict__ Ec)
{
    __shared__ __align__(16) unsigned char As[128 * 128];
    __shared__ __align__(16) unsigned char Bs[128 * 128];

    // swizzle: nwg = 2048 = 8 * 256
    const int d = blockIdx.x;
    const int f = (d & 7) * 256 + (d >> 3);
    const int b = f >> 8;
    const int rem = f & 255;
    const int m0 = (rem >> 4) * 128;  // 16 q-tiles
    const int n0 = (rem & 15) * 128;  // 16 k-tiles

    const int kc_b = cnts[b * 2];
    if (n0 >= kc_b) return;
    const int tid = threadIdx.x, lane = tid & 63, wid = tid >> 6;
    const int wm = (wid >> 1) * 64, wn = (wid & 1) * 64;

    const size_t boff = (size_t)b * Ln * Dn;
    const u16* Tb_b  = Tb  + boff;
    const u16* Xkc_b = Xkc + boff;

    const u16* gA[4]; const u16* gB[4]; int ldsOff[4];
    #pragma unroll
    for (int q = 0; q < 4; ++q) {
        int c = wid * 4 + q;
        int row = c * 8 + (lane >> 3);
        int sig = (lane & 7) ^ (row & 7);
        gA[q] = Tb_b  + (size_t)(m0 + row) * Dn + sig * 8;
        gB[q] = Xkc_b + (size_t)(n0 + row) * Dn + sig * 8;
        ldsOff[q] = c * 1024;
    }

    f32x4 acc[4][4];
    const f32x4 z4 = {0.f, 0.f, 0.f, 0.f};
    #pragma unroll
    for (int i = 0; i < 4; ++i)
        #pragma unroll
        for (int j = 0; j < 4; ++j) acc[i][j] = z4;

    for (int k0 = 0; k0 < Dn; k0 += 64) {
        #pragma unroll
        for (int q = 0; q < 4; ++q) {
            gload16(gA[q], As + ldsOff[q]);
            gload16(gB[q], Bs + ldsOff[q]);
            gA[q] += 64; gB[q] += 64;
        }
        __syncthreads();

        const int sh = lane >> 4;
        #pragma unroll
        for (int s = 0; s < 2; ++s) {
            bf16x8 af[4], bf[4];
            #pragma unroll
            for (int i = 0; i < 4; ++i) {
                int row = wm + i * 16 + (lane & 15);
                af[i] = *(const bf16x8*)(As + row * 128 + (((s * 4 + sh) ^ (row & 7)) << 4));
            }
            #pragma unroll
            for (int j = 0; j < 4; ++j) {
                int row = wn + j * 16 + (lane & 15);
                bf[j] = *(const bf16x8*)(Bs + row * 128 + (((s * 4 + sh) ^ (row & 7)) << 4));
            }
            #pragma unroll
            for (int i = 0; i < 4; ++i)
                #pragma unroll
                for (int j = 0; j < 4; ++j)
                    acc[i][j] = MFMA16(af[i], bf[j], acc[i][j]);
        }
        __syncthreads();
    }

    float vcl[4];
    #pragma unroll
    for (int j = 0; j < 4; ++j) vcl[j] = vc[b * Ln + n0 + wn + j * 16 + (lane & 15)];
    #pragma unroll
    for (int i = 0; i < 4; ++i) {
        #pragma unroll
        for (int r = 0; r < 4; ++r) {
            int m = m0 + wm + i * 16 + (lane >> 4) * 4 + r;
            float um = u[b * Ln + m];
            u16* orow = Ec + ((size_t)(b * Ln + m)) * Ln + n0 + wn;
            #pragma unroll
            for (int j = 0; j < 4; ++j) {
                int jj = n0 + wn + j * 16 + (lane & 15);
                orow[j * 16 + (lane & 15)] =
                    f2bf((jj < kc_b) ? (acc[i][j][r] + um + vcl[j]) : MASKED_VAL);
            }
        }
    }
}

// ---------------------------------------------------------------------------
// stats_expand: one block per (b,q) row.
// If q-unmasked: block-reduce max/sum, write bf16 P row (q-compacted layout).
// Always: expand bf16 Ec row -> full masked f32 e row (kpos gather).
// ---------------------------------------------------------------------------
__global__ __launch_bounds__(256) void stats_expand_kernel(
    const u16* __restrict__ Ec, const int* __restrict__ kpos,
    const int* __restrict__ qpos, const int* __restrict__ cnts,
    u16* __restrict__ Pc, float* __restrict__ e)
{
    __shared__ float redm[4];
    __shared__ float reds[4];
    const int row = blockIdx.x;
    const int b = row >> 11;
    const int t = threadIdx.x;
    const u16* er = Ec + (size_t)row * Ln;
    const int qp = qpos[row];

    if (qp >= 0) {
        const int bound = rup(cnts[b * 2], 64);
        const int lane = t & 63, wave = t >> 6;
        float v[8];
        int base = t * 8;
        if (base < bound) {
            uint4 x = *(const uint4*)(er + base);
            const u16* xs = (const u16*)&x;
            #pragma unroll
            for (int j = 0; j < 8; ++j) v[j] = bf2f(xs[j]);
        } else {
            #pragma unroll
            for (int j = 0; j < 8; ++j) v[j] = MASKED_VAL;
        }

        float mx = v[0];
        #pragma unroll
        for (int j = 1; j < 8; ++j) mx = fmaxf(mx, v[j]);
        #pragma unroll
        for (int o = 32; o > 0; o >>= 1) mx = fmaxf(mx, __shfl_xor(mx, o, 64));
        if (lane == 0) redm[wave] = mx;
        __syncthreads();
        mx = fmaxf(fmaxf(redm[0], redm[1]), fmaxf(redm[2], redm[3]));

        float s = 0.f;
        #pragma unroll
        for (int j = 0; j < 8; ++j) s += __expf(v[j] - mx);
        #pragma unroll
        for (int o = 32; o > 0; o >>= 1) s += __shfl_xor(s, o, 64);
        if (lane == 0) reds[wave] = s;
        __syncthreads();
        s = reds[0] + reds[1] + reds[2] + reds[3];
        float sinv = 1.0f / s;

        // write bf16 P row into q-compacted layout
        u32 P[4];
        #pragma unroll
        for (int j = 0; j < 4; ++j)
            P[j] = pack2(__expf(v[2*j] - mx) * sinv, __expf(v[2*j+1] - mx) * sinv);
        u16* pr = Pc + ((size_t)b * Ln + qp) * Ln + t * 8;
        *(uint4*)pr = make_uint4(P[0], P[1], P[2], P[3]);
    }

    // expansion (reads Ec, writes e; independent of P path)
    const int* kp = kpos + b * Ln;
    const int k = t * 8;
    int p[8];
    *(int4*)&p[0] = *(const int4*)(kp + k);
    *(int4*)&p[4] = *(const int4*)(kp + k + 4);
    float o[8];
    #pragma unroll
    for (int j = 0; j < 8; ++j)
        o[j] = (p[j] >= 0) ? bf2f(er[p[j]]) : MASKED_VAL;

    float* eo = e + (size_t)row * Ln + k;
    *(float4*)(eo)     = make_float4(o[0], o[1], o[2], o[3]);
    *(float4*)(eo + 4) = make_float4(o[4], o[5], o[6], o[7]);
}

// ---------------------------------------------------------------------------
// pvc: a[qidx[i], :] = Pc[b,i,:] @ Vtc^T over compacted k. Pure GEMM:
// A = Pc (q-compacted bf16 P rows, linear), B = Vtc. XCD-chunked grid (1024).
// ---------------------------------------------------------------------------
__global__ __launch_bounds__(256) void pvc_kernel(
    const u16* __restrict__ Pc, const u16* __restrict__ Vtc,
    const int* __restrict__ qidx, const int* __restrict__ cnts,
    float* __restrict__ out_a)
{
    __shared__ __align__(16) unsigned char As[128 * 128];
    __shared__ __align__(16) unsigned char Bs[128 * 128];

    // swizzle: nwg = 1024 = 8 * 128
    const int d = blockIdx.x;
    const int f = (d & 7) * 128 + (d >> 3);
    const int b = f >> 7;
    const int rem = f & 127;
    const int m0 = (rem >> 3) * 128;  // 16 compacted q tiles
    const int n0 = (rem & 7) * 128;   // 8 d tiles

    const int kc_b = cnts[b * 2], qc_b = cnts[b * 2 + 1];
    if (m0 >= rup(qc_b, 128)) return;
    const int kbound = rup(kc_b, 64);
    const int tid = threadIdx.x, lane = tid & 63, wid = tid >> 6;
    const int wm = (wid >> 1) * 64, wn = (wid & 1) * 64;

    const u16* Pc_b  = Pc  + (size_t)b * Ln * Ln;
    const u16* Vtc_b = Vtc + (size_t)b * Dn * Ln;
    const int* qidx_b = qidx + b * Ln;

    const u16* gA[4]; const u16* gB[4]; int ldsOff[4];
    #pragma unroll
    for (int q = 0; q < 4; ++q) {
        int c = wid * 4 + q;
        int row = c * 8 + (lane >> 3);
        int sig = (lane & 7) ^ (row & 7);
        gA[q] = Pc_b  + (size_t)(m0 + row) * Ln + sig * 8;
        gB[q] = Vtc_b + (size_t)(n0 + row) * Ln + sig * 8;
        ldsOff[q] = c * 1024;
    }

    f32x4 acc[4][4];
    const f32x4 z4 = {0.f, 0.f, 0.f, 0.f};
    #pragma unroll
    for (int i = 0; i < 4; ++i)
        #pragma unroll
        for (int j = 0; j < 4; ++j) acc[i][j] = z4;

    for (int k0 = 0; k0 < kbound; k0 += 64) {
        #pragma unroll
        for (int q = 0; q < 4; ++q) {
            gload16(gA[q], As + ldsOff[q]);
            gload16(gB[q], Bs + ldsOff[q]);
            gA[q] += 64; gB[q] += 64;
        }
        __syncthreads();

        const int sh = lane >> 4;
        #pragma unroll
        for (int s = 0; s < 2; ++s) {
            bf16x8 af[4], bv[4];
            #pragma unroll
            for (int i = 0; i < 4; ++i) {
                int row = wm + i * 16 + (lane & 15);
                af[i] = *(const bf16x8*)(As + row * 128 + (((s * 4 + sh) ^ (row & 7)) << 4));
            }
            #pragma unroll
            for (int j = 0; j < 4; ++j) {
                int row = wn + j * 16 + (lane & 15);
                bv[j] = *(const bf16x8*)(Bs + row * 128 + (((s * 4 + sh) ^ (row & 7)) << 4));
            }
            #pragma unroll
            for (int i = 0; i < 4; ++i)
                #pragma unroll
                for (int j = 0; j < 4; ++j)
                    acc[i][j] = MFMA16(af[i], bv[j], acc[i][j]);
        }
        __syncthreads();
    }

    #pragma unroll
    for (int i = 0; i < 4; ++i) {
        #pragma unroll
        for (int r = 0; r < 4; ++r) {
            int gi = m0 + wm + i * 16 + (lane >> 4) * 4 + r;
            if (gi < qc_b) {
                int gm = qidx_b[gi];
                float* orow = out_a + (size_t)(b * Ln + gm) * Dn + n0 + wn;
                #pragma unroll
                for (int j = 0; j < 4; ++j)
                    orow[j * 16 + (lane & 15)] = acc[i][j][r];
            }
        }
    }
}

// ---------------------------------------------------------------------------
extern "C" void kernel_launch(void* const* d_in, const int* in_sizes, int n_in,
                              void* d_out, int out_size, void* d_ws, size_t ws_size,
                              hipStream_t stream)
{
    const float* Q  = (const float*)d_in[0];
    const float* K  = (const float*)d_in[1];
    const float* V  = (const float*)d_in[2];
    const float* Wq = (const float*)d_in[3];
    const float* bq = (const float*)d_in[4];
    const float* Wk = (const float*)d_in[5];
    const float* bk = (const float*)d_in[6];
    const float* Wv = (const float*)d_in[7];
    const float* bv = (const float*)d_in[8];
    const int* q_mask = (const int*)d_in[9];
    const int* k_mask = (const int*)d_in[10];

    float* out_a = (float*)d_out;                       // [B, L, D]
    float* out_e = out_a + (size_t)Bn * Ln * Dn;        // [B, L, L]

    const size_t NE = (size_t)Bn * Ln * Dn;             // 16,777,216
    const size_t NW = (size_t)Dn * Dn;                  // 1,048,576
    const int BL = Bn * Ln;                             // 16,384

    // ws layout:
    //   [Vc, Xq]   -> aliased by Ec (bf16 e', 2*NE) after both are dead
    //   [Tb, Vhc]  -> aliased by Pc (bf16 P,  2*NE) after both are dead
    //   Xkc, Vtc, Wvb, Wqt, Wkt, Mt, small tables
    u16* Vc  = (u16*)d_ws;
    u16* Xq  = Vc + NE;
    u16* Tb  = Xq + NE;
    u16* Vhc = Tb + NE;
    u16* Xkc = Vhc + NE;
    u16* Vtc = Xkc + NE;
    u16* Wvb = Vtc + NE;
    u16* Wqt = Wvb + NW;
    u16* Wkt = Wqt + NW;
    u16* Mt  = Wkt + NW;
    float* w1    = (float*)(Mt + NW);
    float* w2    = w1 + Dn;
    float* cbuf  = w2 + Dn;
    float* uarr  = cbuf + 4;
    float* vc    = uarr + BL;
    int* kidx = (int*)(vc + BL);
    int* kpos = kidx + BL;
    int* qidx = kpos + BL;
    int* qpos = qidx + BL;
    int* cnts = qpos + BL;

    u16* Ec = Vc;   // [B][L][L] bf16, aliases Vc+Xq
    u16* Pc = Tb;   // [B][L][L] bf16 (q-compacted rows), aliases Tb+Vhc

    dim3 blk(256);

    // 0) mask compaction tables
    prep_kernel<<<dim3(Bn), blk, 0, stream>>>(k_mask, q_mask, kidx, kpos, qidx, qpos, cnts);

    // 1) conversions: full Q, compacted-gathered K and V, Wv
    convert_single_kernel<<<dim3(NE / 2048), blk, 0, stream>>>(Q, Xq, (int)NE);
    convgather_kernel<<<dim3(Ln, 2, Bn), blk, 0, stream>>>(K, V, kidx, cnts, Xkc, Vc);
    convert_single_kernel<<<dim3(NW / 2048), blk, 0, stream>>>(Wv, Wvb, (int)NW);

    // 2) weight transposes + bias-fold vectors + c
    wtrans_kernel<<<dim3(16, 16, 2), blk, 0, stream>>>(Wq, Wk, Wqt, Wkt);
    ck_kernel<<<dim3(1), dim3(64), 0, stream>>>(bq, bk, cbuf);
    wvec_kernel<<<dim3(256, 2), blk, 0, stream>>>(Wqt, Wkt, bk, bq, w1, w2);

    // 3) Mt = Wk^T Wq (transposed result), bf16
    mgemm_kernel<<<dim3(8, 8), blk, 0, stream>>>(Wkt, Wqt, Mt);

    // 4) T = Xq @ M ; Vhc = Vc @ Wv^T + bv (compacted rows, linear)
    proj2_kernel<<<dim3(Dn / 128, BL / 128), blk, 0, stream>>>(Xq, Mt, Tb);
    projv_kernel<<<dim3(Dn / 128, Ln / 128, Bn), blk, 0, stream>>>(
        Vc, Wvb, bv, cnts, Vhc);

    // 5) u = Xq.w1 + c (all rows); vc = Xkc.w2 (compacted rows)
    rowdot_kernel<<<dim3(BL / 4, 2), blk, 0, stream>>>(Xq, Xkc, w1, w2, cbuf, uarr, vc);

    // 6) straight transpose of compacted V
    vtransc_kernel<<<dim3(Dn / 64, Ln / 64, Bn), blk, 0, stream>>>(Vhc, cnts, Vtc);

    // 7) compacted scores -> bf16 Ec (overwrites dead Vc/Xq); linear staging
    scorec_kernel<<<dim3(2048), blk, 0, stream>>>(Tb, Xkc, cnts, uarr, vc, Ec);

    // 8) fused stats + bf16 P emission (q-compacted, into dead Tb/Vhc) + e expand
    stats_expand_kernel<<<dim3(BL), blk, 0, stream>>>(Ec, kpos, qpos, cnts, Pc, out_e);

    // 9) zero masked-q rows of a, then pure-GEMM PV
    zeroa_kernel<<<dim3(BL), blk, 0, stream>>>((float4*)out_a, q_mask);
    pvc_kernel<<<dim3(1024), blk, 0, stream>>>(Pc, Vtc, qidx, cnts, out_a);
}

// Round 11
// 339.758 us; speedup vs baseline: 1.4528x; 1.0499x over previous
//
#include <hip/hip_runtime.h>
#include <cstddef>
#include <cstdint>

constexpr int Bn = 8;
constexpr int Ln = 2048;
constexpr int Dn = 1024;
constexpr float MASKED_VAL = -2147483648.0f;  // -2^31

typedef unsigned short u16;
typedef unsigned int   u32;
typedef __attribute__((ext_vector_type(8))) __bf16 bf16x8;
typedef __attribute__((ext_vector_type(4))) float  f32x4;

__device__ __forceinline__ u16 f2bf(float x) {
    u32 u = __float_as_uint(x);
    u += 0x7FFFu + ((u >> 16) & 1u);
    return (u16)(u >> 16);
}
__device__ __forceinline__ float bf2f(u16 h) {
    return __uint_as_float(((u32)h) << 16);
}
__device__ __forceinline__ u32 pack2(float a, float b) {
    return (u32)f2bf(a) | ((u32)f2bf(b) << 16);
}
__device__ __forceinline__ int rup(int x, int m) { return (x + m - 1) & ~(m - 1); }

__device__ __forceinline__ void gload16(const void* g, void* l) {
    typedef const __attribute__((address_space(1))) unsigned int* gp_t;
    typedef __attribute__((address_space(3))) unsigned int* lp_t;
    __builtin_amdgcn_global_load_lds((gp_t)g, (lp_t)l, 16, 0, 0);
}

#define MFMA16(a, b, c) __builtin_amdgcn_mfma_f32_16x16x32_bf16((a), (b), (c), 0, 0, 0)

// ---------------------------------------------------------------------------
// prep: per batch, compaction tables. kidx (padded w/ last valid), kpos
// (-1 if masked), qidx (padded w/ 0), qpos (-1 if masked), counts.
// ---------------------------------------------------------------------------
__global__ __launch_bounds__(256) void prep_kernel(
    const int* __restrict__ k_mask, const int* __restrict__ q_mask,
    int* __restrict__ kidx, int* __restrict__ kpos,
    int* __restrict__ qidx, int* __restrict__ qpos, int* __restrict__ cnts)
{
    __shared__ int sc[256];
    __shared__ int lastv;
    const int b = blockIdx.x, t = threadIdx.x;
    for (int pass = 0; pass < 2; ++pass) {
        const int* msk = (pass ? q_mask : k_mask) + b * Ln;
        int* idx = (pass ? qidx : kidx) + b * Ln;
        int* pos = (pass ? qpos : kpos) + b * Ln;
        int f[8], s = 0;
        #pragma unroll
        for (int j = 0; j < 8; ++j) { f[j] = (msk[t * 8 + j] != 0) ? 1 : 0; s += f[j]; }
        sc[t] = s;
        __syncthreads();
        #pragma unroll
        for (int o = 1; o < 256; o <<= 1) {
            int v = (t >= o) ? sc[t - o] : 0;
            __syncthreads();
            sc[t] += v;
            __syncthreads();
        }
        int incl = sc[t];
        int total = sc[255];
        int p = incl - s;
        #pragma unroll
        for (int j = 0; j < 8; ++j) {
            pos[t * 8 + j] = f[j] ? p : -1;
            if (f[j]) { idx[p] = t * 8 + j; ++p; }
        }
        __syncthreads();
        if (t == 0) {
            cnts[b * 2 + pass] = total;
            lastv = (total > 0) ? idx[total - 1] : 0;
        }
        __syncthreads();
        int padv = (pass == 0) ? lastv : 0;
        for (int e2 = total + t; e2 < Ln; e2 += 256) idx[e2] = padv;
        __syncthreads();
    }
}

// ---------------------------------------------------------------------------
// convert_single: fp32 -> bf16 (full array).
// ---------------------------------------------------------------------------
__global__ __launch_bounds__(256) void convert_single_kernel(
    const float* __restrict__ src, u16* __restrict__ dh, int n)
{
    int i = (blockIdx.x * 256 + threadIdx.x) * 8;
    if (i >= n) return;
    float f[8];
    *(float4*)&f[0] = *(const float4*)(src + i);
    *(float4*)&f[4] = *(const float4*)(src + i + 4);
    u32 H[4];
    #pragma unroll
    for (int j = 0; j < 4; ++j) H[j] = pack2(f[2*j], f[2*j+1]);
    *(uint4*)(dh + i) = make_uint4(H[0], H[1], H[2], H[3]);
}

// ---------------------------------------------------------------------------
// convgather: Xkc[b][j][:] = bf16(K[b][kidx[b][j]][:]) (y=0) and same for
// V->Vc (y=1); only compacted rows j < rup(kc,128). One block per row.
// ---------------------------------------------------------------------------
__global__ __launch_bounds__(256) void convgather_kernel(
    const float* __restrict__ K, const float* __restrict__ V,
    const int* __restrict__ kidx, const int* __restrict__ cnts,
    u16* __restrict__ Xkc, u16* __restrict__ Vc)
{
    const int b = blockIdx.z, j = blockIdx.x, y = blockIdx.y;
    if (j >= rup(cnts[b * 2], 128)) return;
    const int src_row = kidx[b * Ln + j];
    const float* src = (y ? V : K) + ((size_t)b * Ln + src_row) * Dn;
    u16* dst = (y ? Vc : Xkc) + ((size_t)b * Ln + j) * Dn;
    const int t = threadIdx.x;
    float4 f = *(const float4*)(src + t * 4);
    *(uint2*)(dst + t * 4) = make_uint2(pack2(f.x, f.y), pack2(f.z, f.w));
}

// ---------------------------------------------------------------------------
// wtrans: W (fp32 [e][d]) -> Wt (bf16 [d][e]) for Wq and Wk (z selects).
// ---------------------------------------------------------------------------
__global__ __launch_bounds__(256) void wtrans_kernel(
    const float* __restrict__ Wq, const float* __restrict__ Wk,
    u16* __restrict__ Wqt, u16* __restrict__ Wkt)
{
    __shared__ float tile[64][68];
    const float* src = blockIdx.z ? Wk : Wq;
    u16* dst = blockIdx.z ? Wkt : Wqt;
    const int e0 = blockIdx.y * 64, d0 = blockIdx.x * 64;
    const int t = threadIdx.x;
    const int r = t >> 2, cq = (t & 3) * 16;
    const float* s = src + (size_t)(e0 + r) * Dn + d0 + cq;
    #pragma unroll
    for (int i = 0; i < 4; ++i)
        *(float4*)&tile[r][cq + i * 4] = *(const float4*)(s + i * 4);
    __syncthreads();
    u32 o[8];
    #pragma unroll
    for (int i = 0; i < 8; ++i)
        o[i] = pack2(tile[cq + 2 * i][r], tile[cq + 2 * i + 1][r]);
    u16* d = dst + (size_t)(d0 + r) * Dn + e0 + cq;
    *(uint4*)(d)     = make_uint4(o[0], o[1], o[2], o[3]);
    *(uint4*)(d + 8) = make_uint4(o[4], o[5], o[6], o[7]);
}

// ---------------------------------------------------------------------------
// ck: cbuf[0] = bq . bk
// ---------------------------------------------------------------------------
__global__ __launch_bounds__(64) void ck_kernel(
    const float* __restrict__ bq, const float* __restrict__ bk, float* __restrict__ cbuf)
{
    int l = threadIdx.x;
    float s = 0.f;
    #pragma unroll
    for (int i = 0; i < 16; ++i) s += bq[l + 64 * i] * bk[l + 64 * i];
    #pragma unroll
    for (int o = 32; o; o >>= 1) s += __shfl_xor(s, o, 64);
    if (l == 0) cbuf[0] = s;
}

// ---------------------------------------------------------------------------
// wvec: w1[d] = Wqt[d,:].bk ; w2[d] = Wkt[d,:].bq   (one wave per d)
// ---------------------------------------------------------------------------
__global__ __launch_bounds__(256) void wvec_kernel(
    const u16* __restrict__ Wqt, const u16* __restrict__ Wkt,
    const float* __restrict__ bk, const float* __restrict__ bq,
    float* __restrict__ w1, float* __restrict__ w2)
{
    const int y = blockIdx.y;
    const u16* src = y ? Wkt : Wqt;
    const float* vec = y ? bq : bk;
    float* out = y ? w2 : w1;
    const int d = blockIdx.x * 4 + (threadIdx.x >> 6);
    const int l = threadIdx.x & 63;
    float s = 0.f;
    #pragma unroll
    for (int i = 0; i < 16; ++i) {
        int e = l + 64 * i;
        s += bf2f(src[(size_t)d * Dn + e]) * vec[e];
    }
    #pragma unroll
    for (int o = 32; o; o >>= 1) s += __shfl_xor(s, o, 64);
    if (l == 0) out[d] = s;
}

// ---------------------------------------------------------------------------
// rowdot: y=0: u[row] = Xq[row,:].w1 + c (all rows);
//         y=1: vc[row] = Xkc[row,:].w2 (compacted rows; pad rows harmless).
// ---------------------------------------------------------------------------
__global__ __launch_bounds__(256) void rowdot_kernel(
    const u16* __restrict__ Xq, const u16* __restrict__ Xkc,
    const float* __restrict__ w1, const float* __restrict__ w2,
    const float* __restrict__ cbuf, float* __restrict__ u, float* __restrict__ vc)
{
    const int y = blockIdx.y;
    const u16* x = y ? Xkc : Xq;
    const float* w = y ? w2 : w1;
    float* out = y ? vc : u;
    const int row = blockIdx.x * 4 + (threadIdx.x >> 6);
    const int l = threadIdx.x & 63;
    float s = 0.f;
    #pragma unroll
    for (int h = 0; h < 2; ++h) {
        const u16* xp = x + (size_t)row * Dn + h * 512 + l * 8;
        const float* wp = w + h * 512 + l * 8;
        uint4 xv = *(const uint4*)xp;
        float4 wa = *(const float4*)(wp);
        float4 wb = *(const float4*)(wp + 4);
        const u16* xs = (const u16*)&xv;
        s += bf2f(xs[0]) * wa.x + bf2f(xs[1]) * wa.y + bf2f(xs[2]) * wa.z + bf2f(xs[3]) * wa.w
           + bf2f(xs[4]) * wb.x + bf2f(xs[5]) * wb.y + bf2f(xs[6]) * wb.z + bf2f(xs[7]) * wb.w;
    }
    #pragma unroll
    for (int o = 32; o; o >>= 1) s += __shfl_xor(s, o, 64);
    if (l == 0) out[row] = s + (y ? 0.0f : cbuf[0]);
}

// ---------------------------------------------------------------------------
// zeroa: zero a-rows where q_mask==0 (pvc writes all other rows fully).
// ---------------------------------------------------------------------------
__global__ __launch_bounds__(256) void zeroa_kernel(
    float4* __restrict__ out_a, const int* __restrict__ q_mask)
{
    const int row = blockIdx.x;
    if (q_mask[row]) return;
    out_a[(size_t)row * 256 + threadIdx.x] = make_float4(0.f, 0.f, 0.f, 0.f);
}

// ---------------------------------------------------------------------------
// mgemm: C[m][n] = sum_e A[m,e] * B[n,e]  (1024x1024x1024, bf16 out).
// Called with (Wqt, Wkt) -> Mb[m][n] = (Wq^T Wk)[m][n]  (row-major M).
// ---------------------------------------------------------------------------
__global__ __launch_bounds__(256) void mgemm_kernel(
    const u16* __restrict__ A, const u16* __restrict__ B, u16* __restrict__ C)
{
    __shared__ __align__(16) unsigned char As[128 * 128];
    __shared__ __align__(16) unsigned char Bs[128 * 128];

    const int m0 = blockIdx.y * 128, n0 = blockIdx.x * 128;
    const int tid = threadIdx.x, lane = tid & 63, wid = tid >> 6;
    const int wm = (wid >> 1) * 64, wn = (wid & 1) * 64;

    const u16* gA[4]; const u16* gB[4]; int ldsOff[4];
    #pragma unroll
    for (int q = 0; q < 4; ++q) {
        int c = wid * 4 + q;
        int row = c * 8 + (lane >> 3);
        int sig = (lane & 7) ^ (row & 7);
        gA[q] = A + (size_t)(m0 + row) * Dn + sig * 8;
        gB[q] = B + (size_t)(n0 + row) * Dn + sig * 8;
        ldsOff[q] = c * 1024;
    }

    f32x4 acc[4][4];
    const f32x4 z4 = {0.f, 0.f, 0.f, 0.f};
    #pragma unroll
    for (int i = 0; i < 4; ++i)
        #pragma unroll
        for (int j = 0; j < 4; ++j) acc[i][j] = z4;

    for (int k0 = 0; k0 < Dn; k0 += 64) {
        #pragma unroll
        for (int q = 0; q < 4; ++q) {
            gload16(gA[q], As + ldsOff[q]);
            gload16(gB[q], Bs + ldsOff[q]);
            gA[q] += 64; gB[q] += 64;
        }
        __syncthreads();

        const int sh = lane >> 4;
        #pragma unroll
        for (int s = 0; s < 2; ++s) {
            bf16x8 af[4], bf[4];
            #pragma unroll
            for (int i = 0; i < 4; ++i) {
                int row = wm + i * 16 + (lane & 15);
                af[i] = *(const bf16x8*)(As + row * 128 + (((s * 4 + sh) ^ (row & 7)) << 4));
            }
            #pragma unroll
            for (int j = 0; j < 4; ++j) {
                int row = wn + j * 16 + (lane & 15);
                bf[j] = *(const bf16x8*)(Bs + row * 128 + (((s * 4 + sh) ^ (row & 7)) << 4));
            }
            #pragma unroll
            for (int i = 0; i < 4; ++i)
                #pragma unroll
                for (int j = 0; j < 4; ++j)
                    acc[i][j] = MFMA16(af[i], bf[j], acc[i][j]);
        }
        __syncthreads();
    }

    #pragma unroll
    for (int i = 0; i < 4; ++i) {
        #pragma unroll
        for (int r = 0; r < 4; ++r) {
            int m = m0 + wm + i * 16 + (lane >> 4) * 4 + r;
            u16* oh = C + (size_t)m * Dn + n0 + wn;
            #pragma unroll
            for (int j = 0; j < 4; ++j)
                oh[j * 16 + (lane & 15)] = f2bf(acc[i][j][r]);
        }
    }
}

// ---------------------------------------------------------------------------
// gt: Gt[b][j][:] = Xkc[b][j][:] @ Mb^T  i.e. Gt[j][d] = sum_e Xkc[j,e]M[d,e]
// compacted rows only. Clone of projv without bias, B = Mb [D x D].
// ---------------------------------------------------------------------------
__global__ __launch_bounds__(256) void gt_kernel(
    const u16* __restrict__ Xkc, const u16* __restrict__ Mb,
    const int* __restrict__ cnts, u16* __restrict__ Gt)
{
    __shared__ __align__(16) unsigned char As[128 * 128];
    __shared__ __align__(16) unsigned char Bs[128 * 128];

    const int b = blockIdx.z;
    const int kc_b = cnts[b * 2];
    const int m0 = blockIdx.y * 128;
    if (m0 >= rup(kc_b, 128)) return;
    const int n0 = blockIdx.x * 128;
    const int tid = threadIdx.x, lane = tid & 63, wid = tid >> 6;
    const int wm = (wid >> 1) * 64, wn = (wid & 1) * 64;

    const u16* Xkc_b = Xkc + (size_t)b * Ln * Dn;

    const u16* gA[4]; const u16* gB[4]; int ldsOff[4];
    #pragma unroll
    for (int q = 0; q < 4; ++q) {
        int c = wid * 4 + q;
        int row = c * 8 + (lane >> 3);
        int sig = (lane & 7) ^ (row & 7);
        gA[q] = Xkc_b + (size_t)(m0 + row) * Dn + sig * 8;
        gB[q] = Mb + (size_t)(n0 + row) * Dn + sig * 8;
        ldsOff[q] = c * 1024;
    }

    f32x4 acc[4][4];
    const f32x4 z4 = {0.f, 0.f, 0.f, 0.f};
    #pragma unroll
    for (int i = 0; i < 4; ++i)
        #pragma unroll
        for (int j = 0; j < 4; ++j) acc[i][j] = z4;

    for (int k0 = 0; k0 < Dn; k0 += 64) {
        #pragma unroll
        for (int q = 0; q < 4; ++q) {
            gload16(gA[q], As + ldsOff[q]);
            gload16(gB[q], Bs + ldsOff[q]);
            gA[q] += 64; gB[q] += 64;
        }
        __syncthreads();

        const int sh = lane >> 4;
        #pragma unroll
        for (int s = 0; s < 2; ++s) {
            bf16x8 af[4], bf[4];
            #pragma unroll
            for (int i = 0; i < 4; ++i) {
                int row = wm + i * 16 + (lane & 15);
                af[i] = *(const bf16x8*)(As + row * 128 + (((s * 4 + sh) ^ (row & 7)) << 4));
            }
            #pragma unroll
            for (int j = 0; j < 4; ++j) {
                int row = wn + j * 16 + (lane & 15);
                bf[j] = *(const bf16x8*)(Bs + row * 128 + (((s * 4 + sh) ^ (row & 7)) << 4));
            }
            #pragma unroll
            for (int i = 0; i < 4; ++i)
                #pragma unroll
                for (int j = 0; j < 4; ++j)
                    acc[i][j] = MFMA16(af[i], bf[j], acc[i][j]);
        }
        __syncthreads();
    }

    u16* Gt_b = Gt + (size_t)b * Ln * Dn;
    #pragma unroll
    for (int i = 0; i < 4; ++i) {
        #pragma unroll
        for (int r = 0; r < 4; ++r) {
            int m = m0 + wm + i * 16 + (lane >> 4) * 4 + r;
            u16* oh = Gt_b + (size_t)m * Dn + n0 + wn;
            #pragma unroll
            for (int j = 0; j < 4; ++j)
                oh[j * 16 + (lane & 15)] = f2bf(acc[i][j][r]);
        }
    }
}

// ---------------------------------------------------------------------------
// projv: Vhc[b][j][:] = Vc[b][j][:] @ Wvb^T + bv (compacted rows, linear A).
// ---------------------------------------------------------------------------
__global__ __launch_bounds__(256) void projv_kernel(
    const u16* __restrict__ Vc, const u16* __restrict__ Wvb,
    const float* __restrict__ bv, const int* __restrict__ cnts,
    u16* __restrict__ Vhc)
{
    __shared__ __align__(16) unsigned char As[128 * 128];
    __shared__ __align__(16) unsigned char Bs[128 * 128];

    const int b = blockIdx.z;
    const int kc_b = cnts[b * 2];
    const int m0 = blockIdx.y * 128;
    if (m0 >= rup(kc_b, 128)) return;
    const int n0 = blockIdx.x * 128;
    const int tid = threadIdx.x, lane = tid & 63, wid = tid >> 6;
    const int wm = (wid >> 1) * 64, wn = (wid & 1) * 64;

    const u16* Vc_b = Vc + (size_t)b * Ln * Dn;

    const u16* gA[4]; const u16* gB[4]; int ldsOff[4];
    #pragma unroll
    for (int q = 0; q < 4; ++q) {
        int c = wid * 4 + q;
        int row = c * 8 + (lane >> 3);
        int sig = (lane & 7) ^ (row & 7);
        gA[q] = Vc_b + (size_t)(m0 + row) * Dn + sig * 8;
        gB[q] = Wvb + (size_t)(n0 + row) * Dn + sig * 8;
        ldsOff[q] = c * 1024;
    }

    f32x4 acc[4][4];
    const f32x4 z4 = {0.f, 0.f, 0.f, 0.f};
    #pragma unroll
    for (int i = 0; i < 4; ++i)
        #pragma unroll
        for (int j = 0; j < 4; ++j) acc[i][j] = z4;

    for (int k0 = 0; k0 < Dn; k0 += 64) {
        #pragma unroll
        for (int q = 0; q < 4; ++q) {
            gload16(gA[q], As + ldsOff[q]);
            gload16(gB[q], Bs + ldsOff[q]);
            gA[q] += 64; gB[q] += 64;
        }
        __syncthreads();

        const int sh = lane >> 4;
        #pragma unroll
        for (int s = 0; s < 2; ++s) {
            bf16x8 af[4], bf[4];
            #pragma unroll
            for (int i = 0; i < 4; ++i) {
                int row = wm + i * 16 + (lane & 15);
                af[i] = *(const bf16x8*)(As + row * 128 + (((s * 4 + sh) ^ (row & 7)) << 4));
            }
            #pragma unroll
            for (int j = 0; j < 4; ++j) {
                int row = wn + j * 16 + (lane & 15);
                bf[j] = *(const bf16x8*)(Bs + row * 128 + (((s * 4 + sh) ^ (row & 7)) << 4));
            }
            #pragma unroll
            for (int i = 0; i < 4; ++i)
                #pragma unroll
                for (int j = 0; j < 4; ++j)
                    acc[i][j] = MFMA16(af[i], bf[j], acc[i][j]);
        }
        __syncthreads();
    }

    float bv4[4];
    #pragma unroll
    for (int j = 0; j < 4; ++j) bv4[j] = bv[n0 + wn + j * 16 + (lane & 15)];
    u16* Vhc_b = Vhc + (size_t)b * Ln * Dn;
    #pragma unroll
    for (int i = 0; i < 4; ++i) {
        #pragma unroll
        for (int r = 0; r < 4; ++r) {
            int m = m0 + wm + i * 16 + (lane >> 4) * 4 + r;
            u16* oh = Vhc_b + (size_t)m * Dn + n0 + wn;
            #pragma unroll
            for (int j = 0; j < 4; ++j)
                oh[j * 16 + (lane & 15)] = f2bf(acc[i][j][r] + bv4[j]);
        }
    }
}

// ---------------------------------------------------------------------------
// vtransc: Vtc[b][d][j] = Vhc[b][j][d]  (straight transpose, compacted rows)
// ---------------------------------------------------------------------------
__global__ __launch_bounds__(256) void vtransc_kernel(
    const u16* __restrict__ Vhc, const int* __restrict__ cnts,
    u16* __restrict__ Vtc)
{
    __shared__ u16 tile[64][72];
    const int b = blockIdx.z;
    const int l0 = blockIdx.y * 64, d0 = blockIdx.x * 64;
    if (l0 >= rup(cnts[b * 2], 64)) return;
    const int t = threadIdx.x;
    const int r = t >> 2, cq = (t & 3) * 16;

    const u16* src = Vhc + (size_t)(b * Ln + l0 + r) * Dn + d0 + cq;
    *(uint4*)&tile[r][cq]     = *(const uint4*)(src);
    *(uint4*)&tile[r][cq + 8] = *(const uint4*)(src + 8);
    __syncthreads();

    u16 tmp[16];
    #pragma unroll
    for (int i = 0; i < 16; ++i) tmp[i] = tile[cq + i][r];
    u16* dst = Vtc + (size_t)b * Dn * Ln + (size_t)(d0 + r) * Ln + l0 + cq;
    *(uint4*)(dst)     = *(uint4*)&tmp[0];
    *(uint4*)(dst + 8) = *(uint4*)&tmp[8];
}

// ---------------------------------------------------------------------------
// scorec: Ec[b,q,j] = bf16( Xq[b,q,:].Gt[b,j,:] + u[b,q] + vc[b,j] )
// for compacted j < kc; pad cols get bf16(MASKED). All-linear staging.
// XCD-chunked 1D grid (2048).
// ---------------------------------------------------------------------------
__global__ __launch_bounds__(256) void scorec_kernel(
    const u16* __restrict__ Xq, const u16* __restrict__ Gt,
    const int* __restrict__ cnts,
    const float* __restrict__ u, const float* __restrict__ vc,
    u16* __restrict__ Ec)
{
    __shared__ __align__(16) unsigned char As[128 * 128];
    __shared__ __align__(16) unsigned char Bs[128 * 128];

    // swizzle: nwg = 2048 = 8 * 256
    const int d = blockIdx.x;
    const int f = (d & 7) * 256 + (d >> 3);
    const int b = f >> 8;
    const int rem = f & 255;
    const int m0 = (rem >> 4) * 128;  // 16 q-tiles
    const int n0 = (rem & 15) * 128;  // 16 k-tiles

    const int kc_b = cnts[b * 2];
    if (n0 >= kc_b) return;
    const int tid = threadIdx.x, lane = tid & 63, wid = tid >> 6;
    const int wm = (wid >> 1) * 64, wn = (wid & 1) * 64;

    const size_t boff = (size_t)b * Ln * Dn;
    const u16* Xq_b = Xq + boff;
    const u16* Gt_b = Gt + boff;

    const u16* gA[4]; const u16* gB[4]; int ldsOff[4];
    #pragma unroll
    for (int q = 0; q < 4; ++q) {
        int c = wid * 4 + q;
        int row = c * 8 + (lane >> 3);
        int sig = (lane & 7) ^ (row & 7);
        gA[q] = Xq_b + (size_t)(m0 + row) * Dn + sig * 8;
        gB[q] = Gt_b + (size_t)(n0 + row) * Dn + sig * 8;
        ldsOff[q] = c * 1024;
    }

    f32x4 acc[4][4];
    const f32x4 z4 = {0.f, 0.f, 0.f, 0.f};
    #pragma unroll
    for (int i = 0; i < 4; ++i)
        #pragma unroll
        for (int j = 0; j < 4; ++j) acc[i][j] = z4;

    for (int k0 = 0; k0 < Dn; k0 += 64) {
        #pragma unroll
        for (int q = 0; q < 4; ++q) {
            gload16(gA[q], As + ldsOff[q]);
            gload16(gB[q], Bs + ldsOff[q]);
            gA[q] += 64; gB[q] += 64;
        }
        __syncthreads();

        const int sh = lane >> 4;
        #pragma unroll
        for (int s = 0; s < 2; ++s) {
            bf16x8 af[4], bf[4];
            #pragma unroll
            for (int i = 0; i < 4; ++i) {
                int row = wm + i * 16 + (lane & 15);
                af[i] = *(const bf16x8*)(As + row * 128 + (((s * 4 + sh) ^ (row & 7)) << 4));
            }
            #pragma unroll
            for (int j = 0; j < 4; ++j) {
                int row = wn + j * 16 + (lane & 15);
                bf[j] = *(const bf16x8*)(Bs + row * 128 + (((s * 4 + sh) ^ (row & 7)) << 4));
            }
            #pragma unroll
            for (int i = 0; i < 4; ++i)
                #pragma unroll
                for (int j = 0; j < 4; ++j)
                    acc[i][j] = MFMA16(af[i], bf[j], acc[i][j]);
        }
        __syncthreads();
    }

    float vcl[4];
    #pragma unroll
    for (int j = 0; j < 4; ++j) vcl[j] = vc[b * Ln + n0 + wn + j * 16 + (lane & 15)];
    #pragma unroll
    for (int i = 0; i < 4; ++i) {
        #pragma unroll
        for (int r = 0; r < 4; ++r) {
            int m = m0 + wm + i * 16 + (lane >> 4) * 4 + r;
            float um = u[b * Ln + m];
            u16* orow = Ec + ((size_t)(b * Ln + m)) * Ln + n0 + wn;
            #pragma unroll
            for (int j = 0; j < 4; ++j) {
                int jj = n0 + wn + j * 16 + (lane & 15);
                orow[j * 16 + (lane & 15)] =
                    f2bf((jj < kc_b) ? (acc[i][j][r] + um + vcl[j]) : MASKED_VAL);
            }
        }
    }
}

// ---------------------------------------------------------------------------
// stats_expand: one block per (b,q) row.
// If q-unmasked: block-reduce max/sum, write bf16 P row (q-compacted layout).
// Always: expand bf16 Ec row -> full masked f32 e row (kpos gather).
// ---------------------------------------------------------------------------
__global__ __launch_bounds__(256) void stats_expand_kernel(
    const u16* __restrict__ Ec, const int* __restrict__ kpos,
    const int* __restrict__ qpos, const int* __restrict__ cnts,
    u16* __restrict__ Pc, float* __restrict__ e)
{
    __shared__ float redm[4];
    __shared__ float reds[4];
    const int row = blockIdx.x;
    const int b = row >> 11;
    const int t = threadIdx.x;
    const u16* er = Ec + (size_t)row * Ln;
    const int qp = qpos[row];

    if (qp >= 0) {
        const int bound = rup(cnts[b * 2], 64);
        const int lane = t & 63, wave = t >> 6;
        float v[8];
        int base = t * 8;
        if (base < bound) {
            uint4 x = *(const uint4*)(er + base);
            const u16* xs = (const u16*)&x;
            #pragma unroll
            for (int j = 0; j < 8; ++j) v[j] = bf2f(xs[j]);
        } else {
            #pragma unroll
            for (int j = 0; j < 8; ++j) v[j] = MASKED_VAL;
        }

        float mx = v[0];
        #pragma unroll
        for (int j = 1; j < 8; ++j) mx = fmaxf(mx, v[j]);
        #pragma unroll
        for (int o = 32; o > 0; o >>= 1) mx = fmaxf(mx, __shfl_xor(mx, o, 64));
        if (lane == 0) redm[wave] = mx;
        __syncthreads();
        mx = fmaxf(fmaxf(redm[0], redm[1]), fmaxf(redm[2], redm[3]));

        float s = 0.f;
        #pragma unroll
        for (int j = 0; j < 8; ++j) s += __expf(v[j] - mx);
        #pragma unroll
        for (int o = 32; o > 0; o >>= 1) s += __shfl_xor(s, o, 64);
        if (lane == 0) reds[wave] = s;
        __syncthreads();
        s = reds[0] + reds[1] + reds[2] + reds[3];
        float sinv = 1.0f / s;

        // write bf16 P row into q-compacted layout
        u32 P[4];
        #pragma unroll
        for (int j = 0; j < 4; ++j)
            P[j] = pack2(__expf(v[2*j] - mx) * sinv, __expf(v[2*j+1] - mx) * sinv);
        u16* pr = Pc + ((size_t)b * Ln + qp) * Ln + t * 8;
        *(uint4*)pr = make_uint4(P[0], P[1], P[2], P[3]);
    }

    // expansion (reads Ec, writes e; independent of P path)
    const int* kp = kpos + b * Ln;
    const int k = t * 8;
    int p[8];
    *(int4*)&p[0] = *(const int4*)(kp + k);
    *(int4*)&p[4] = *(const int4*)(kp + k + 4);
    float o[8];
    #pragma unroll
    for (int j = 0; j < 8; ++j)
        o[j] = (p[j] >= 0) ? bf2f(er[p[j]]) : MASKED_VAL;

    float* eo = e + (size_t)row * Ln + k;
    *(float4*)(eo)     = make_float4(o[0], o[1], o[2], o[3]);
    *(float4*)(eo + 4) = make_float4(o[4], o[5], o[6], o[7]);
}

// ---------------------------------------------------------------------------
// pvc: a[qidx[i], :] = Pc[b,i,:] @ Vtc^T over compacted k. Pure GEMM:
// A = Pc (q-compacted bf16 P rows, linear), B = Vtc. XCD-chunked grid (1024).
// ---------------------------------------------------------------------------
__global__ __launch_bounds__(256) void pvc_kernel(
    const u16* __restrict__ Pc, const u16* __restrict__ Vtc,
    const int* __restrict__ qidx, const int* __restrict__ cnts,
    float* __restrict__ out_a)
{
    __shared__ __align__(16) unsigned char As[128 * 128];
    __shared__ __align__(16) unsigned char Bs[128 * 128];

    // swizzle: nwg = 1024 = 8 * 128
    const int d = blockIdx.x;
    const int f = (d & 7) * 128 + (d >> 3);
    const int b = f >> 7;
    const int rem = f & 127;
    const int m0 = (rem >> 3) * 128;  // 16 compacted q tiles
    const int n0 = (rem & 7) * 128;   // 8 d tiles

    const int kc_b = cnts[b * 2], qc_b = cnts[b * 2 + 1];
    if (m0 >= rup(qc_b, 128)) return;
    const int kbound = rup(kc_b, 64);
    const int tid = threadIdx.x, lane = tid & 63, wid = tid >> 6;
    const int wm = (wid >> 1) * 64, wn = (wid & 1) * 64;

    const u16* Pc_b  = Pc  + (size_t)b * Ln * Ln;
    const u16* Vtc_b = Vtc + (size_t)b * Dn * Ln;
    const int* qidx_b = qidx + b * Ln;

    const u16* gA[4]; const u16* gB[4]; int ldsOff[4];
    #pragma unroll
    for (int q = 0; q < 4; ++q) {
        int c = wid * 4 + q;
        int row = c * 8 + (lane >> 3);
        int sig = (lane & 7) ^ (row & 7);
        gA[q] = Pc_b  + (size_t)(m0 + row) * Ln + sig * 8;
        gB[q] = Vtc_b + (size_t)(n0 + row) * Ln + sig * 8;
        ldsOff[q] = c * 1024;
    }

    f32x4 acc[4][4];
    const f32x4 z4 = {0.f, 0.f, 0.f, 0.f};
    #pragma unroll
    for (int i = 0; i < 4; ++i)
        #pragma unroll
        for (int j = 0; j < 4; ++j) acc[i][j] = z4;

    for (int k0 = 0; k0 < kbound; k0 += 64) {
        #pragma unroll
        for (int q = 0; q < 4; ++q) {
            gload16(gA[q], As + ldsOff[q]);
            gload16(gB[q], Bs + ldsOff[q]);
            gA[q] += 64; gB[q] += 64;
        }
        __syncthreads();

        const int sh = lane >> 4;
        #pragma unroll
        for (int s = 0; s < 2; ++s) {
            bf16x8 af[4], bv[4];
            #pragma unroll
            for (int i = 0; i < 4; ++i) {
                int row = wm + i * 16 + (lane & 15);
                af[i] = *(const bf16x8*)(As + row * 128 + (((s * 4 + sh) ^ (row & 7)) << 4));
            }
            #pragma unroll
            for (int j = 0; j < 4; ++j) {
                int row = wn + j * 16 + (lane & 15);
                bv[j] = *(const bf16x8*)(Bs + row * 128 + (((s * 4 + sh) ^ (row & 7)) << 4));
            }
            #pragma unroll
            for (int i = 0; i < 4; ++i)
                #pragma unroll
                for (int j = 0; j < 4; ++j)
                    acc[i][j] = MFMA16(af[i], bv[j], acc[i][j]);
        }
        __syncthreads();
    }

    #pragma unroll
    for (int i = 0; i < 4; ++i) {
        #pragma unroll
        for (int r = 0; r < 4; ++r) {
            int gi = m0 + wm + i * 16 + (lane >> 4) * 4 + r;
            if (gi < qc_b) {
                int gm = qidx_b[gi];
                float* orow = out_a + (size_t)(b * Ln + gm) * Dn + n0 + wn;
                #pragma unroll
                for (int j = 0; j < 4; ++j)
                    orow[j * 16 + (lane & 15)] = acc[i][j][r];
            }
        }
    }
}

// ---------------------------------------------------------------------------
extern "C" void kernel_launch(void* const* d_in, const int* in_sizes, int n_in,
                              void* d_out, int out_size, void* d_ws, size_t ws_size,
                              hipStream_t stream)
{
    const float* Q  = (const float*)d_in[0];
    const float* K  = (const float*)d_in[1];
    const float* V  = (const float*)d_in[2];
    const float* Wq = (const float*)d_in[3];
    const float* bq = (const float*)d_in[4];
    const float* Wk = (const float*)d_in[5];
    const float* bk = (const float*)d_in[6];
    const float* Wv = (const float*)d_in[7];
    const float* bv = (const float*)d_in[8];
    const int* q_mask = (const int*)d_in[9];
    const int* k_mask = (const int*)d_in[10];

    float* out_a = (float*)d_out;                       // [B, L, D]
    float* out_e = out_a + (size_t)Bn * Ln * Dn;        // [B, L, L]

    const size_t NE = (size_t)Bn * Ln * Dn;             // 16,777,216
    const size_t NW = (size_t)Dn * Dn;                  // 1,048,576
    const int BL = Bn * Ln;                             // 16,384

    // ws layout (aliasing plan):
    //   [Vc, Xkc]  -> aliased by Ec (bf16 e', 2*NE) after both are dead
    //   [Gt, Vhc]  -> aliased by Pc (bf16 P,  2*NE) after both are dead
    //   Xq, Vtc, Wvb, Wqt, Wkt, Mb, small tables
    u16* Vc  = (u16*)d_ws;
    u16* Xkc = Vc + NE;
    u16* Gt  = Xkc + NE;
    u16* Vhc = Gt + NE;
    u16* Xq  = Vhc + NE;
    u16* Vtc = Xq + NE;
    u16* Wvb = Vtc + NE;
    u16* Wqt = Wvb + NW;
    u16* Wkt = Wqt + NW;
    u16* Mb  = Wkt + NW;
    float* w1    = (float*)(Mb + NW);
    float* w2    = w1 + Dn;
    float* cbuf  = w2 + Dn;
    float* uarr  = cbuf + 4;
    float* vc    = uarr + BL;
    int* kidx = (int*)(vc + BL);
    int* kpos = kidx + BL;
    int* qidx = kpos + BL;
    int* qpos = qidx + BL;
    int* cnts = qpos + BL;

    u16* Ec = Vc;   // [B][L][L] bf16, aliases Vc+Xkc (dead after projv/gt/rowdot)
    u16* Pc = Gt;   // [B][L][L] bf16 (q-compacted rows), aliases Gt+Vhc

    dim3 blk(256);

    // 0) mask compaction tables
    prep_kernel<<<dim3(Bn), blk, 0, stream>>>(k_mask, q_mask, kidx, kpos, qidx, qpos, cnts);

    // 1) conversions: full Q, compacted-gathered K and V, Wv
    convert_single_kernel<<<dim3(NE / 2048), blk, 0, stream>>>(Q, Xq, (int)NE);
    convgather_kernel<<<dim3(Ln, 2, Bn), blk, 0, stream>>>(K, V, kidx, cnts, Xkc, Vc);
    convert_single_kernel<<<dim3(NW / 2048), blk, 0, stream>>>(Wv, Wvb, (int)NW);

    // 2) weight transposes + bias-fold vectors + c
    wtrans_kernel<<<dim3(16, 16, 2), blk, 0, stream>>>(Wq, Wk, Wqt, Wkt);
    ck_kernel<<<dim3(1), dim3(64), 0, stream>>>(bq, bk, cbuf);
    wvec_kernel<<<dim3(256, 2), blk, 0, stream>>>(Wqt, Wkt, bk, bq, w1, w2);

    // 3) Mb = Wq^T Wk (row-major M), bf16
    mgemm_kernel<<<dim3(8, 8), blk, 0, stream>>>(Wqt, Wkt, Mb);

    // 4) Gt[b] = Xkc[b] @ M^T (compacted rows); Vhc = Vc @ Wv^T + bv
    gt_kernel<<<dim3(Dn / 128, Ln / 128, Bn), blk, 0, stream>>>(Xkc, Mb, cnts, Gt);
    projv_kernel<<<dim3(Dn / 128, Ln / 128, Bn), blk, 0, stream>>>(
        Vc, Wvb, bv, cnts, Vhc);

    // 5) u = Xq.w1 + c (all rows); vc = Xkc.w2 (compacted rows)
    rowdot_kernel<<<dim3(BL / 4, 2), blk, 0, stream>>>(Xq, Xkc, w1, w2, cbuf, uarr, vc);

    // 6) straight transpose of compacted V
    vtransc_kernel<<<dim3(Dn / 64, Ln / 64, Bn), blk, 0, stream>>>(Vhc, cnts, Vtc);

    // 7) compacted scores (Xq . Gt + u + vc) -> bf16 Ec (overwrites Vc/Xkc)
    scorec_kernel<<<dim3(2048), blk, 0, stream>>>(Xq, Gt, cnts, uarr, vc, Ec);

    // 8) fused stats + bf16 P emission (q-compacted, into dead Gt/Vhc) + e expand
    stats_expand_kernel<<<dim3(BL), blk, 0, stream>>>(Ec, kpos, qpos, cnts, Pc, out_e);

    // 9) zero masked-q rows of a, then pure-GEMM PV
    zeroa_kernel<<<dim3(BL), blk, 0, stream>>>((float4*)out_a, q_mask);
    pvc_kernel<<<dim3(1024), blk, 0, stream>>>(Pc, Vtc, qidx, cnts, out_a);
}